// Round 6
// baseline (648.015 us; speedup 1.0000x reference)
//
#include <hip/hip_runtime.h>
#include <hip/hip_bf16.h>
#include <math.h>

typedef unsigned short ushort;
typedef unsigned int uint;

// Sizes (fixed by the reference problem)
#define NV 200     // N nodes
#define DEG 199
#define HID 96
#define KG 20      // groups / one-hot width
#define MG 10      // group size
#define AJR 30
#define NH 4
#define HD 118     // HID + 2 + K
#define DM 472     // NH*HD
#define NN 40000   // N*N
#define NT 20100   // N*(N+1)/2 unique (i<=j) pairs: S[(i,j)] == S[(j,i)]
#define NTP 20160  // NT rounded up to 64 (315 blocks * 64 rows)

// Workspace layout (float units).
#define WS_BASE   0
#define WS_H1     19200
#define WS_H2     38400
#define WS_HFULL  57600
#define WS_GMEAN  81200
#define WS_KHF    194952   // khfT [DM][NV] = 94400 floats (transposed!)
#define WS_VHF    289352
#define WS_B1     383752   // after k_SC: reused for C (softmax row consts)
#define WS_B2     478152
#define WS_SC1    572552
#define WS_SC2    732552
#define WS_Z      892552             // Z fp32: 4*224*472 = 422,912 floats
#define WS_ZT     1315464            // ZT bf16: 512*896 ushorts = 229,376 floats
#define WS_E1     1544840            // E1 fp32 [NH][NV][224] = 179,200 floats
#define WS_E2     1724040            // E2 fp32 [NH][NV][224]
#define WS_M1     1903240            // M1 fp32 [NH][NV] = 800
#define WS_M2     1904040            // M2
// end = 1,904,840 floats = 7.62 MB  (v6's run proved ws_size >= 42.3 MB)

// Output layout (floats)
#define OFF_H   18880000
#define OFF_HF  18899200
#define OFF_Q   18922800

typedef __attribute__((ext_vector_type(8))) short short8v;
typedef __attribute__((ext_vector_type(4))) float float4v;

__device__ __forceinline__ float bf2f(uint u) {
  return __uint_as_float(u << 16);
}
__device__ __forceinline__ ushort f2bf(float f) {
  uint u = __float_as_uint(f);
  uint r = (u + 0x7fffu + ((u >> 16) & 1u)) >> 16;  // RNE
  return (ushort)r;
}
__device__ __forceinline__ uint packbf(float a, float b) {
  __hip_bfloat162 h2 = __float22bfloat162_rn(make_float2(a, b));
  union { __hip_bfloat162 h; uint u; } c;
  c.h = h2;
  return c.u;
}

// Packed upper-triangle index p (0..NT-1) -> (i,j), i<=j.
__device__ __forceinline__ int triOff(int i) {
  return i * 200 - ((i * (i - 1)) >> 1);
}
__device__ __forceinline__ void p2ij(int p, int& io, int& jo) {
  float s = sqrtf((float)(160801 - 8 * p));   // (2N+1)^2 - 8p
  int i = (int)((401.0f - s) * 0.5f);
  if (i < 0) i = 0;
  if (i > 199) i = 199;
  while (i > 0 && triOff(i) > p) --i;
  while (i < 199 && triOff(i + 1) <= p) ++i;
  io = i;
  jo = i + (p - triOff(i));
}

// ---------------------------------------------------------------------------
// A: iteration-invariant part of the GCN update
// ---------------------------------------------------------------------------
__global__ __launch_bounds__(256) void k_base(
    const float* __restrict__ x, const float* __restrict__ dmat,
    const float* __restrict__ label,
    const float* __restrict__ l0w, const float* __restrict__ l0b,
    const float* __restrict__ l1w, const float* __restrict__ l1b,
    const float* __restrict__ l2b, const float* __restrict__ l3b,
    const float* __restrict__ l4w, const float* __restrict__ l4b,
    const float* __restrict__ l5w, const float* __restrict__ l5b,
    float* __restrict__ base) {
  int i = blockIdx.x; int t = threadIdx.x;
  int g = i / MG;
  __shared__ float sv[256];
  __shared__ float sn2[9];
  float v = -1.0f;
  if (t < DEG) {
    int u = (t < i) ? t : t + 1;
    if (u / MG != g) v = dmat[i * DEG + t];
  }
  sv[t] = v;
  __syncthreads();
  for (int k2 = 2; k2 <= 256; k2 <<= 1) {
    for (int jj = k2 >> 1; jj > 0; jj >>= 1) {
      int ixj = t ^ jj;
      if (ixj > t) {
        float a = sv[t], b = sv[ixj];
        bool sw = ((t & k2) == 0) ? (a < b) : (a > b);
        if (sw) { sv[t] = b; sv[ixj] = a; }
      }
      __syncthreads();
    }
  }
  if (t == 0) {
    float tmp[9];
    for (int q = 0; q < 9; q++) tmp[q] = dmat[i * DEG + MG * g + q];
    for (int a2 = 1; a2 < 9; a2++) {
      float key = tmp[a2]; int b2 = a2 - 1;
      while (b2 >= 0 && tmp[b2] < key) { tmp[b2 + 1] = tmp[b2]; b2--; }
      tmp[b2 + 1] = key;
    }
    for (int q = 0; q < 9; q++) sn2[q] = tmp[q];
  }
  __syncthreads();
  if (t < HID) {
    float acc = l0b[t] + l1b[t] + l2b[t] + l3b[t] + l4b[t] + l5b[t];
    acc += x[i * 2 + 0] * l0w[t] + x[i * 2 + 1] * l0w[HID + t];
    for (int k = 0; k < KG; k++) acc += label[i * KG + k] * l1w[k * HID + t];
    for (int q = 0; q < AJR; q++) acc += sv[q] * l4w[q * HID + t];
    for (int q = 0; q < 9; q++) acc += sn2[q] * l5w[q * HID + t];
    base[i * HID + t] = acc;
  }
}

// ---------------------------------------------------------------------------
// B: one GCN step
// ---------------------------------------------------------------------------
__global__ __launch_bounds__(192) void k_gcn(
    const float* __restrict__ hin, const float* __restrict__ base,
    const float* __restrict__ w, const float* __restrict__ l2w,
    const float* __restrict__ l3w, float* __restrict__ hout) {
  int i = blockIdx.x; int t = threadIdx.x;
  int g = i / MG;
  __shared__ float n1[HID], n2[HID];
  if (t < HID) {
    float acc = 0.f, wsum = 0.f;
    for (int j = 0; j < DEG; j++) {
      int u = (j < i) ? j : j + 1;
      if (u / MG != g) {
        float wj = w[i * DEG + j];
        acc += wj * hin[u * HID + t];
        wsum += wj;
      }
    }
    n1[t] = acc / wsum;
  } else if (t < 2 * HID) {
    int dd = t - HID;
    float acc = 0.f, wsum = 0.f;
    for (int u = MG * g; u < MG * g + MG; u++) {
      if (u == i) continue;
      int j = (u < i) ? u : u - 1;
      float wj = w[i * DEG + j];
      acc += wj * hin[u * HID + dd];
      wsum += wj;
    }
    n2[dd] = acc / wsum;
  }
  __syncthreads();
  if (t < HID) {
    float acc = base[i * HID + t];
    for (int dd = 0; dd < HID; dd++)
      acc += n1[dd] * l2w[dd * HID + t] + n2[dd] * l3w[dd * HID + t];
    hout[i * HID + t] = fmaxf(acc, 0.f);
  }
}

// ---------------------------------------------------------------------------
// C1: h_full assembly (+ h, h_full outputs)
// ---------------------------------------------------------------------------
__global__ __launch_bounds__(128) void k_hfull(
    const float* __restrict__ h, const float* __restrict__ x,
    const float* __restrict__ label, const int* __restrict__ remain_step,
    float* __restrict__ hfull, float* __restrict__ out_h,
    float* __restrict__ out_hf) {
  int i = blockIdx.x; int t = threadIdx.x;
  if (t < HD) {
    float v;
    if (t < HID) {
      int p = *remain_step;
      int t2 = t & ~1;
      float div = expf(-(float)t2 * (logf(10000.f) / (float)HID));
      float ang = (float)p * div;
      float pe = (t & 1) ? cosf(ang) : sinf(ang);
      float hv = h[i * HID + t];
      out_h[i * HID + t] = hv;
      v = hv + pe;
    } else if (t < HID + 2) {
      v = x[i * 2 + (t - HID)];
    } else {
      v = label[i * KG + (t - HID - 2)];
    }
    hfull[i * HD + t] = v;
    out_hf[i * HD + t] = v;
  }
}

// C2: group means of h_full
__global__ __launch_bounds__(128) void k_gmean(
    const float* __restrict__ hfull, float* __restrict__ gmean) {
  int g = blockIdx.x; int t = threadIdx.x;
  if (t < HD) {
    float s = 0.f;
    for (int q = 0; q < MG; q++) s += hfull[(g * MG + q) * HD + t];
    gmean[g * HD + t] = s * 0.1f;
  }
}

// ---------------------------------------------------------------------------
// D: fused k_wsum + k_kv + k_B.
//   khfT[c][i] = b0v[c] + d0+d1+d2+d3        (khf TRANSPOSED for k_SC reads)
//   vhf[i][c]  = b1v[c] + e0+e1+e2+e3
//   B1[i][c]   = d0 + g2
//   B2[i][c]   = b0v[c] + d1 + g3
// ---------------------------------------------------------------------------
__global__ __launch_bounds__(256) void k_kvB(
    const float* __restrict__ hfull, const float* __restrict__ gmean,
    const float* __restrict__ w0, const float* __restrict__ b0v,
    const float* __restrict__ w1, const float* __restrict__ b1v,
    float* __restrict__ khfT, float* __restrict__ vhf,
    float* __restrict__ B1, float* __restrict__ B2) {
  int i = blockIdx.x; int t = threadIdx.x; int g = i / MG;
  __shared__ float hr[HD], gr[HD];
  if (t < HD) { hr[t] = hfull[i * HD + t]; gr[t] = gmean[g * HD + t]; }
  __syncthreads();
  for (int c = t; c < DM; c += 256) {
    const float* w0c = w0 + c;
    const float* w1c = w1 + c;
    float d0 = 0.f, d1 = 0.f, d2 = 0.f, d3 = 0.f;
    float g2 = 0.f, g3 = 0.f;
    float e0 = 0.f, e1 = 0.f, e2 = 0.f, e3 = 0.f;
    for (int dd = 0; dd < HD; dd++) {
      float hv = hr[dd], gv = gr[dd];
      float a0 = w0c[dd * DM];
      float a1 = w0c[(HD + dd) * DM];
      float a2 = w0c[(2 * HD + dd) * DM];
      float a3 = w0c[(3 * HD + dd) * DM];
      d0 += hv * a0; d1 += hv * a1; d2 += hv * a2; d3 += hv * a3;
      g2 += gv * a2; g3 += gv * a3;
      e0 += hv * w1c[dd * DM];
      e1 += hv * w1c[(HD + dd) * DM];
      e2 += hv * w1c[(2 * HD + dd) * DM];
      e3 += hv * w1c[(3 * HD + dd) * DM];
    }
    float b0c = b0v[c];
    khfT[c * NV + i] = b0c + d0 + d1 + d2 + d3;
    vhf[i * DM + c] = b1v[c] + e0 + e1 + e2 + e3;
    B1[i * DM + c] = d0 + g2;
    B2[i * DM + c] = b0c + d1 + g3;
  }
}

// D4: score components; khfT is [c][k] so the k-gather is coalesced.
__global__ __launch_bounds__(256) void k_SC(
    const float* __restrict__ B1, const float* __restrict__ B2,
    const float* __restrict__ khfT, float* __restrict__ SC1,
    float* __restrict__ SC2) {
  int i = blockIdx.x; int t = threadIdx.x;
  const float scl = 1.4426950408889634f / sqrtf((float)HD);
  __shared__ float b1r[DM], b2r[DM];
  for (int c = t; c < DM; c += 256) { b1r[c] = B1[i * DM + c]; b2r[c] = B2[i * DM + c]; }
  __syncthreads();
  for (int p = t; p < NH * NV; p += 256) {
    int h = p / NV, k = p - h * NV;
    float s1a = 0.f, s2a = 0.f;
    const float* kc = khfT + (size_t)h * HD * NV + k;
    const float* b1h = b1r + h * HD;
    const float* b2h = b2r + h * HD;
    for (int dd = 0; dd < HD; dd++) {
      float kv = kc[dd * NV];
      s1a += b1h[dd] * kv;
      s2a += b2h[dd] * kv;
    }
    SC1[h * NN + i * NV + k] = s1a * scl;
    SC2[h * NN + i * NV + k] = s2a * scl;
  }
}

// D5: softmax row constants C[h][i][j] = m + log2(l), coalesced row scans.
__global__ __launch_bounds__(256) void k_ml(
    const float* __restrict__ SC1, const float* __restrict__ SC2,
    float* __restrict__ C) {
  int i = blockIdx.x, h = blockIdx.y;
  int t = threadIdx.x;
  __shared__ float s1s[224];
  for (int k = t; k < 224; k += 256)
    s1s[k] = (k < NV) ? SC1[h * NN + i * NV + k] : -1e30f;
  __syncthreads();
  int l = t & 31;
  int g = t >> 5;
  const float* s2b = SC2 + h * NN;
  for (int it = 0; it < 25; ++it) {
    int j = it * 8 + g;
    const float* row = s2b + j * NV;
    float v[7];
#pragma unroll
    for (int e = 0; e < 7; ++e) {
      int k = l + 32 * e;
      v[e] = (k < NV) ? (s1s[k] + row[k]) : -1e30f;
    }
    float m = v[0];
#pragma unroll
    for (int e = 1; e < 7; ++e) m = fmaxf(m, v[e]);
#pragma unroll
    for (int off = 16; off > 0; off >>= 1) m = fmaxf(m, __shfl_xor(m, off, 32));
    float s = 0.f;
#pragma unroll
    for (int e = 0; e < 7; ++e) s += exp2f(v[e] - m);
#pragma unroll
    for (int off = 16; off > 0; off >>= 1) s += __shfl_xor(s, off, 32);
    if (l == 0) C[h * NN + i * NV + j] = m + log2f(s);
  }
}

// ---------------------------------------------------------------------------
// D6 (v7): row-normalized exponential tables.
// m1[h][i] = max_k SC1[h,i,k];  E1[h][i][k] = 2^(SC1-m1), 0 for k>=200.
// Same for E2/m2. One wave per (i,h); 800 blocks. E arrays are 1.4 MB
// total -> L2-resident (unlike v6's 36 MB P, which was the regression).
// ---------------------------------------------------------------------------
__global__ __launch_bounds__(64) void k_E(
    const float* __restrict__ SC1, const float* __restrict__ SC2,
    float* __restrict__ E1, float* __restrict__ E2,
    float* __restrict__ M1, float* __restrict__ M2) {
  int i = blockIdx.x, h = blockIdx.y;
  int l = threadIdx.x;
  const float* s1 = SC1 + h * NN + i * NV;
  const float* s2 = SC2 + h * NN + i * NV;
  float v1[4], v2[4];
  float m1 = -1e30f, m2 = -1e30f;
#pragma unroll
  for (int e = 0; e < 4; ++e) {
    int k = l + 64 * e;
    if (k < NV) {
      v1[e] = s1[k]; v2[e] = s2[k];
      m1 = fmaxf(m1, v1[e]); m2 = fmaxf(m2, v2[e]);
    } else {
      v1[e] = -1e30f; v2[e] = -1e30f;
    }
  }
#pragma unroll
  for (int off = 32; off > 0; off >>= 1) {
    m1 = fmaxf(m1, __shfl_xor(m1, off));
    m2 = fmaxf(m2, __shfl_xor(m2, off));
  }
  float* d1 = E1 + (size_t)(h * NV + i) * 224;
  float* d2 = E2 + (size_t)(h * NV + i) * 224;
#pragma unroll
  for (int e = 0; e < 4; ++e) {
    int k = l + 64 * e;
    if (k < 224) {
      d1[k] = (k < NV) ? exp2f(v1[e] - m1) : 0.f;
      d2[k] = (k < NV) ? exp2f(v2[e] - m2) : 0.f;
    }
  }
  if (l == 0) { M1[h * NV + i] = m1; M2[h * NV + i] = m2; }
}

// ---------------------------------------------------------------------------
// E1: Z[h][k][c] = sum_d vhf[k][h*HD+d] * w3[(h*HD+d)*DM + c]  (fp32)
// ---------------------------------------------------------------------------
__global__ __launch_bounds__(256) void k_Z(
    const float* __restrict__ vhf, const float* __restrict__ w3,
    float* __restrict__ Z) {
  int k = blockIdx.x, h = blockIdx.y;
  int t = threadIdx.x;
  __shared__ float vr[HD];
  if (t < HD) vr[t] = vhf[k * DM + h * HD + t];
  __syncthreads();
  for (int c = t; c < DM; c += 256) {
    float a = 0.f;
    for (int d = 0; d < HD; ++d) a += vr[d] * w3[(h * HD + d) * DM + c];
    Z[((size_t)h * 224 + k) * DM + c] = a;
  }
}

// E2: ZT[c][h*224+kk] = bf16(Z[h][kk][c]) zero-padded. 512x896.
__global__ __launch_bounds__(256) void k_ZT(
    const float* __restrict__ Z, ushort* __restrict__ ZT) {
  int idx = blockIdx.x * 256 + threadIdx.x;  // < 512*896
  if (idx < 512 * 896) {
    int c = idx / 896, kp = idx - c * 896;
    int h = kp / 224, kk = kp - h * 224;
    ushort v = 0;
    if (c < DM && kk < NV) v = f2bf(Z[((size_t)h * 224 + kk) * DM + c]);
    ZT[idx] = v;
  }
}

// ---------------------------------------------------------------------------
// F (v7): fused attention+output GEMM over UNIQUE row pairs with FACTORED
// exponentials:
//   P[p][h,k] = si * E1[h,i,k]*E2[h,j,k] + sj * E1[h,j,k]*E2[h,i,k]
//   si = 2^(m1_i+m2_j-C_ij), sj = 2^(m1_j+m2_i-C_ji)   (2 exp2 per row-head)
// Inner loop is pure FMA (no transcendentals) - v5's 46% VALUBusy was exp2.
// Tile 64 rows x 256 cols, grid (2,315)=630 blocks, 4 waves each 16 rows x
// 256 cols (acc[16]=64 VGPR, 16 MFMA per barrier pair = half of v5's barrier
// count). E zero-padding (k>=200) removes the kvalid branch. Mirror write.
// ---------------------------------------------------------------------------
__global__ __launch_bounds__(256) void k_sfusedE(
    const float* __restrict__ E1, const float* __restrict__ E2,
    const float* __restrict__ M1, const float* __restrict__ M2,
    const float* __restrict__ C, const ushort* __restrict__ ZT,
    const float* __restrict__ b3, float* __restrict__ outS) {
  int t = threadIdx.x;
  int c0 = blockIdx.x * 256, p0 = blockIdx.y * 64;
  int lane = t & 63, wm = t >> 6;
  int frow = lane & 15, quad = lane >> 4;
  __shared__ __align__(16) ushort Bs[256 * 40];
  int p = p0 + wm * 16 + frow;
  bool bval = (p < NT);
  int iA = 0, jA = 0;
  if (bval) p2ij(p, iA, jA);
  float4v acc[16];
#pragma unroll
  for (int n = 0; n < 16; ++n) acc[n] = (float4v)(0.f);

  for (int h = 0; h < NH; ++h) {
    const float* e1i = E1 + (size_t)(h * NV + iA) * 224;
    const float* e2i = E2 + (size_t)(h * NV + iA) * 224;
    const float* e1j = E1 + (size_t)(h * NV + jA) * 224;
    const float* e2j = E2 + (size_t)(h * NV + jA) * 224;
    float si = 0.f, sj = 0.f;
    if (bval) {
      si = exp2f(M1[h * NV + iA] + M2[h * NV + jA] - C[h * NN + iA * NV + jA]);
      sj = exp2f(M1[h * NV + jA] + M2[h * NV + iA] - C[h * NN + jA * NV + iA]);
    }
    for (int ks = 0; ks < 7; ++ks) {
      int kb = ks * 32 + quad * 8;
      // --- issue B-tile loads early (hide under A-gen FMA) ---
      uint4 bq[4];
#pragma unroll
      for (int qq = 0; qq < 4; ++qq) {
        int li = qq * 256 + t;           // 0..1023
        int c = li >> 2;                 // 0..255
        int ko = (li & 3) * 8;
        bq[qq] = *(const uint4*)(ZT + (size_t)(c0 + c) * 896 + h * 224 +
                                 ks * 32 + ko);
      }
      // --- A fragment: pure FMA, no exp2, no branch (E zero-padded) ---
      float4 A1 = *(const float4*)(e1i + kb), A1b = *(const float4*)(e1i + kb + 4);
      float4 B2 = *(const float4*)(e2j + kb), B2b = *(const float4*)(e2j + kb + 4);
      float4 D1 = *(const float4*)(e1j + kb), D1b = *(const float4*)(e1j + kb + 4);
      float4 E2v = *(const float4*)(e2i + kb), E2b = *(const float4*)(e2i + kb + 4);
      float p0_ = si * (A1.x * B2.x) + sj * (D1.x * E2v.x);
      float p1_ = si * (A1.y * B2.y) + sj * (D1.y * E2v.y);
      float p2_ = si * (A1.z * B2.z) + sj * (D1.z * E2v.z);
      float p3_ = si * (A1.w * B2.w) + sj * (D1.w * E2v.w);
      float p4_ = si * (A1b.x * B2b.x) + sj * (D1b.x * E2b.x);
      float p5_ = si * (A1b.y * B2b.y) + sj * (D1b.y * E2b.y);
      float p6_ = si * (A1b.z * B2b.z) + sj * (D1b.z * E2b.z);
      float p7_ = si * (A1b.w * B2b.w) + sj * (D1b.w * E2b.w);
      union { uint4 q; short8v v; } af;
      af.q.x = packbf(p0_, p1_);
      af.q.y = packbf(p2_, p3_);
      af.q.z = packbf(p4_, p5_);
      af.q.w = packbf(p6_, p7_);
      __syncthreads();  // previous step's MFMA reads of Bs complete
#pragma unroll
      for (int qq = 0; qq < 4; ++qq) {
        int li = qq * 256 + t;
        int c = li >> 2;
        int ko = (li & 3) * 8;
        *(uint4*)&Bs[c * 40 + ko] = bq[qq];
      }
      __syncthreads();
      // --- MFMA: 16 column fragments ---
#pragma unroll
      for (int n = 0; n < 16; ++n) {
        short8v bf = *(const short8v*)&Bs[(n * 16 + frow) * 40 + quad * 8];
        acc[n] = __builtin_amdgcn_mfma_f32_16x16x32_bf16(af.v, bf, acc[n],
                                                         0, 0, 0);
      }
    }
  }
  // epilogue: C/D layout col=lane&15, row=quad*4+reg; mirror to (j,i).
  int ie[4], je[4];
#pragma unroll
  for (int r2 = 0; r2 < 4; ++r2) {
    int pe = p0 + wm * 16 + quad * 4 + r2;
    if (pe < NT) {
      p2ij(pe, ie[r2], je[r2]);
    } else {
      ie[r2] = -1; je[r2] = 0;
    }
  }
#pragma unroll
  for (int n = 0; n < 16; ++n) {
    int c = c0 + n * 16 + frow;
    if (c >= DM) continue;
    float bb = 2.0f * b3[c];
#pragma unroll
    for (int r2 = 0; r2 < 4; ++r2) {
      int ii = ie[r2];
      if (ii < 0) continue;
      int jj = je[r2];
      float v = acc[n][r2] + bb;
      outS[(size_t)(ii * NV + jj) * DM + c] = v;
      if (ii != jj) outS[(size_t)(jj * NV + ii) * DM + c] = v;
    }
  }
}

// ---------------------------------------------------------------------------
// G: Q_sa = relu(S@v1+b1)@v2 + b2, over unique (i<=j) rows; mirrored.
// ---------------------------------------------------------------------------
__global__ __launch_bounds__(256) void k_qsaT(
    const float* __restrict__ S, const float* __restrict__ v1w,
    const float* __restrict__ v1b, const float* __restrict__ v2w,
    const float* __restrict__ v2b, float* __restrict__ outQ) {
  __shared__ float Ss[64][9];
  __shared__ float V1s[8][48];
  __shared__ float Ts[64][49];
  __shared__ int rowI[64], rowJ[64];
  int t = threadIdx.x;
  int p0b = blockIdx.x * 64;
  if (t < 64) {
    int p = p0b + t;
    if (p < NT) {
      int ii, jj; p2ij(p, ii, jj);
      rowI[t] = ii; rowJ[t] = jj;
    } else {
      rowI[t] = -1; rowJ[t] = 0;
    }
  }
  int ty = t >> 4, tx = t & 15;
  int lr = t >> 2, lk = (t & 3) * 2;
  __syncthreads();
  int riS = rowI[lr];
  size_t srow = (riS >= 0) ? (size_t)(riS * NV + rowJ[lr]) * DM : 0;
  float acc[4][3];
#pragma unroll
  for (int y = 0; y < 4; y++)
#pragma unroll
    for (int xx = 0; xx < 3; xx++) acc[y][xx] = 0.f;
  for (int k0 = 0; k0 < DM; k0 += 8) {
    __syncthreads();
    Ss[lr][lk] = S[srow + k0 + lk];
    Ss[lr][lk + 1] = S[srow + k0 + lk + 1];
    if (t < 192) {
      int e = t * 2; int kk = e / 48, c = e - kk * 48;
      V1s[kk][c] = v1w[(k0 + kk) * 48 + c];
      V1s[kk][c + 1] = v1w[(k0 + kk) * 48 + c + 1];
    }
    __syncthreads();
#pragma unroll
    for (int kk = 0; kk < 8; kk++) {
      float a0 = Ss[ty * 4 + 0][kk], a1 = Ss[ty * 4 + 1][kk],
            a2 = Ss[ty * 4 + 2][kk], a3 = Ss[ty * 4 + 3][kk];
      float w0_ = V1s[kk][tx * 3 + 0], w1_ = V1s[kk][tx * 3 + 1],
            w2_ = V1s[kk][tx * 3 + 2];
      acc[0][0] += a0 * w0_; acc[0][1] += a0 * w1_; acc[0][2] += a0 * w2_;
      acc[1][0] += a1 * w0_; acc[1][1] += a1 * w1_; acc[1][2] += a1 * w2_;
      acc[2][0] += a2 * w0_; acc[2][1] += a2 * w1_; acc[2][2] += a2 * w2_;
      acc[3][0] += a3 * w0_; acc[3][1] += a3 * w1_; acc[3][2] += a3 * w2_;
    }
  }
#pragma unroll
  for (int y = 0; y < 4; y++)
#pragma unroll
    for (int xx = 0; xx < 3; xx++)
      Ts[ty * 4 + y][tx * 3 + xx] = fmaxf(acc[y][xx] + v1b[tx * 3 + xx], 0.f);
  __syncthreads();
  if (t < 64 && rowI[t] >= 0) {
    float q = v2b[0];
    for (int c = 0; c < 48; c++) q += Ts[t][c] * v2w[c];
    int ii = rowI[t], jj = rowJ[t];
    outQ[ii * NV + jj] = q;
    if (ii != jj) outQ[jj * NV + ii] = q;
  }
}

// ---------------------------------------------------------------------------
extern "C" void kernel_launch(void* const* d_in, const int* in_sizes, int n_in,
                              void* d_out, int out_size, void* d_ws,
                              size_t ws_size, hipStream_t stream) {
  const float* x = (const float*)d_in[0];
  const float* label = (const float*)d_in[1];
  const float* h0 = (const float*)d_in[2];
  const float* w = (const float*)d_in[3];
  const float* dmat = (const float*)d_in[4];
  const float* l0w = (const float*)d_in[5];
  const float* l0b = (const float*)d_in[6];
  const float* l1w = (const float*)d_in[7];
  const float* l1b = (const float*)d_in[8];
  const float* l2w = (const float*)d_in[9];
  const float* l2b = (const float*)d_in[10];
  const float* l3w = (const float*)d_in[11];
  const float* l3b = (const float*)d_in[12];
  const float* l4w = (const float*)d_in[13];
  const float* l4b = (const float*)d_in[14];
  const float* l5w = (const float*)d_in[15];
  const float* l5b = (const float*)d_in[16];
  const float* w0 = (const float*)d_in[17];
  const float* b0v = (const float*)d_in[18];
  const float* w1 = (const float*)d_in[19];
  const float* b1v = (const float*)d_in[20];
  const float* w3 = (const float*)d_in[21];
  const float* b3 = (const float*)d_in[22];
  const float* v1w = (const float*)d_in[23];
  const float* v1b = (const float*)d_in[24];
  const float* v2w = (const float*)d_in[25];
  const float* v2b = (const float*)d_in[26];
  const int* remain_step = (const int*)d_in[29];

  float* ws = (float*)d_ws;
  float* base = ws + WS_BASE;
  float* h1 = ws + WS_H1;
  float* h2 = ws + WS_H2;
  float* hfull = ws + WS_HFULL;
  float* gmean = ws + WS_GMEAN;
  float* khfT = ws + WS_KHF;
  float* vhf = ws + WS_VHF;
  float* B1 = ws + WS_B1;
  float* B2 = ws + WS_B2;
  float* SC1 = ws + WS_SC1;
  float* SC2 = ws + WS_SC2;
  float* Z = ws + WS_Z;
  ushort* ZT = (ushort*)(ws + WS_ZT);
  float* E1 = ws + WS_E1;
  float* E2 = ws + WS_E2;
  float* M1 = ws + WS_M1;
  float* M2 = ws + WS_M2;
  float* C = ws + WS_B1;  // reuses B1/B2 slots after k_SC

  float* outS = (float*)d_out;
  float* outH = outS + OFF_H;
  float* outHF = outS + OFF_HF;
  float* outQ = outS + OFF_Q;

  k_base<<<NV, 256, 0, stream>>>(x, dmat, label, l0w, l0b, l1w, l1b, l2b, l3b,
                                 l4w, l4b, l5w, l5b, base);
  k_gcn<<<NV, 192, 0, stream>>>(h0, base, w, l2w, l3w, h1);
  k_gcn<<<NV, 192, 0, stream>>>(h1, base, w, l2w, l3w, h2);
  k_hfull<<<NV, 128, 0, stream>>>(h2, x, label, remain_step, hfull, outH, outHF);
  k_gmean<<<KG, 128, 0, stream>>>(hfull, gmean);
  k_kvB<<<NV, 256, 0, stream>>>(hfull, gmean, w0, b0v, w1, b1v, khfT, vhf, B1,
                                B2);
  k_Z<<<dim3(NV, NH), 256, 0, stream>>>(vhf, w3, Z);
  k_ZT<<<(512 * 896 + 255) / 256, 256, 0, stream>>>(Z, ZT);
  k_SC<<<NV, 256, 0, stream>>>(B1, B2, khfT, SC1, SC2);
  k_ml<<<dim3(NV, NH), 256, 0, stream>>>(SC1, SC2, C);
  k_E<<<dim3(NV, NH), 64, 0, stream>>>(SC1, SC2, E1, E2, M1, M2);
  k_sfusedE<<<dim3(2, NTP / 64), 256, 0, stream>>>(E1, E2, M1, M2, C, ZT, b3,
                                                   outS);
  k_qsaT<<<(NT + 63) / 64, 256, 0, stream>>>(outS, v1w, v1b, v2w, v2b, outQ);
}

// Round 7
// 637.939 us; speedup vs baseline: 1.0158x; 1.0158x over previous
//
#include <hip/hip_runtime.h>
#include <hip/hip_bf16.h>
#include <math.h>

typedef unsigned short ushort;
typedef unsigned int uint;

// Sizes (fixed by the reference problem)
#define NV 200     // N nodes
#define DEG 199
#define HID 96
#define KG 20      // groups / one-hot width
#define MG 10      // group size
#define AJR 30
#define NH 4
#define HD 118     // HID + 2 + K
#define DM 472     // NH*HD
#define NN 40000   // N*N
#define NT 20100   // N*(N+1)/2 unique (i<=j) pairs: S[(i,j)] == S[(j,i)]
#define NTP 20160  // NT rounded up to 64 (315 blocks * 64 rows)

// Workspace layout (float units).
#define WS_BASE   0
#define WS_H1     19200
#define WS_H2     38400
#define WS_HFULL  57600
#define WS_GMEAN  81200
#define WS_KHF    194952   // khfT [DM][NV] = 94400 floats (transposed!)
#define WS_VHF    289352
#define WS_B1     383752   // after k_SC: reused for C (softmax row consts)
#define WS_B2     478152
#define WS_SC1    572552
#define WS_SC2    732552
#define WS_Z      892552             // Z fp32: 4*224*472 = 422,912 floats
#define WS_ZT     1315464            // ZT bf16: 512*896 ushorts = 229,376 floats
#define WS_E1     1544840            // E1 fp32 [NV][896] node-major = 179,200
#define WS_E2     1724040            // E2 fp32 [NV][896]
#define WS_M1     1903240            // M1 fp32 [NH][NV] = 800
#define WS_M2     1904040            // M2

// Output layout (floats)
#define OFF_H   18880000
#define OFF_HF  18899200
#define OFF_Q   18922800

typedef __attribute__((ext_vector_type(8))) short short8v;
typedef __attribute__((ext_vector_type(4))) float float4v;

__device__ __forceinline__ float bf2f(uint u) {
  return __uint_as_float(u << 16);
}
__device__ __forceinline__ ushort f2bf(float f) {
  uint u = __float_as_uint(f);
  uint r = (u + 0x7fffu + ((u >> 16) & 1u)) >> 16;  // RNE
  return (ushort)r;
}
__device__ __forceinline__ uint packbf(float a, float b) {
  __hip_bfloat162 h2 = __float22bfloat162_rn(make_float2(a, b));
  union { __hip_bfloat162 h; uint u; } c;
  c.h = h2;
  return c.u;
}

// Packed upper-triangle index p (0..NT-1) -> (i,j), i<=j.
__device__ __forceinline__ int triOff(int i) {
  return i * 200 - ((i * (i - 1)) >> 1);
}
__device__ __forceinline__ void p2ij(int p, int& io, int& jo) {
  float s = sqrtf((float)(160801 - 8 * p));   // (2N+1)^2 - 8p
  int i = (int)((401.0f - s) * 0.5f);
  if (i < 0) i = 0;
  if (i > 199) i = 199;
  while (i > 0 && triOff(i) > p) --i;
  while (i < 199 && triOff(i + 1) <= p) ++i;
  io = i;
  jo = i + (p - triOff(i));
}

// ---------------------------------------------------------------------------
// A: iteration-invariant part of the GCN update
// ---------------------------------------------------------------------------
__global__ __launch_bounds__(256) void k_base(
    const float* __restrict__ x, const float* __restrict__ dmat,
    const float* __restrict__ label,
    const float* __restrict__ l0w, const float* __restrict__ l0b,
    const float* __restrict__ l1w, const float* __restrict__ l1b,
    const float* __restrict__ l2b, const float* __restrict__ l3b,
    const float* __restrict__ l4w, const float* __restrict__ l4b,
    const float* __restrict__ l5w, const float* __restrict__ l5b,
    float* __restrict__ base) {
  int i = blockIdx.x; int t = threadIdx.x;
  int g = i / MG;
  __shared__ float sv[256];
  __shared__ float sn2[9];
  float v = -1.0f;
  if (t < DEG) {
    int u = (t < i) ? t : t + 1;
    if (u / MG != g) v = dmat[i * DEG + t];
  }
  sv[t] = v;
  __syncthreads();
  for (int k2 = 2; k2 <= 256; k2 <<= 1) {
    for (int jj = k2 >> 1; jj > 0; jj >>= 1) {
      int ixj = t ^ jj;
      if (ixj > t) {
        float a = sv[t], b = sv[ixj];
        bool sw = ((t & k2) == 0) ? (a < b) : (a > b);
        if (sw) { sv[t] = b; sv[ixj] = a; }
      }
      __syncthreads();
    }
  }
  if (t == 0) {
    float tmp[9];
    for (int q = 0; q < 9; q++) tmp[q] = dmat[i * DEG + MG * g + q];
    for (int a2 = 1; a2 < 9; a2++) {
      float key = tmp[a2]; int b2 = a2 - 1;
      while (b2 >= 0 && tmp[b2] < key) { tmp[b2 + 1] = tmp[b2]; b2--; }
      tmp[b2 + 1] = key;
    }
    for (int q = 0; q < 9; q++) sn2[q] = tmp[q];
  }
  __syncthreads();
  if (t < HID) {
    float acc = l0b[t] + l1b[t] + l2b[t] + l3b[t] + l4b[t] + l5b[t];
    acc += x[i * 2 + 0] * l0w[t] + x[i * 2 + 1] * l0w[HID + t];
    for (int k = 0; k < KG; k++) acc += label[i * KG + k] * l1w[k * HID + t];
    for (int q = 0; q < AJR; q++) acc += sv[q] * l4w[q * HID + t];
    for (int q = 0; q < 9; q++) acc += sn2[q] * l5w[q * HID + t];
    base[i * HID + t] = acc;
  }
}

// ---------------------------------------------------------------------------
// B: one GCN step
// ---------------------------------------------------------------------------
__global__ __launch_bounds__(192) void k_gcn(
    const float* __restrict__ hin, const float* __restrict__ base,
    const float* __restrict__ w, const float* __restrict__ l2w,
    const float* __restrict__ l3w, float* __restrict__ hout) {
  int i = blockIdx.x; int t = threadIdx.x;
  int g = i / MG;
  __shared__ float n1[HID], n2[HID];
  if (t < HID) {
    float acc = 0.f, wsum = 0.f;
    for (int j = 0; j < DEG; j++) {
      int u = (j < i) ? j : j + 1;
      if (u / MG != g) {
        float wj = w[i * DEG + j];
        acc += wj * hin[u * HID + t];
        wsum += wj;
      }
    }
    n1[t] = acc / wsum;
  } else if (t < 2 * HID) {
    int dd = t - HID;
    float acc = 0.f, wsum = 0.f;
    for (int u = MG * g; u < MG * g + MG; u++) {
      if (u == i) continue;
      int j = (u < i) ? u : u - 1;
      float wj = w[i * DEG + j];
      acc += wj * hin[u * HID + dd];
      wsum += wj;
    }
    n2[dd] = acc / wsum;
  }
  __syncthreads();
  if (t < HID) {
    float acc = base[i * HID + t];
    for (int dd = 0; dd < HID; dd++)
      acc += n1[dd] * l2w[dd * HID + t] + n2[dd] * l3w[dd * HID + t];
    hout[i * HID + t] = fmaxf(acc, 0.f);
  }
}

// ---------------------------------------------------------------------------
// C1: h_full assembly (+ h, h_full outputs)
// ---------------------------------------------------------------------------
__global__ __launch_bounds__(128) void k_hfull(
    const float* __restrict__ h, const float* __restrict__ x,
    const float* __restrict__ label, const int* __restrict__ remain_step,
    float* __restrict__ hfull, float* __restrict__ out_h,
    float* __restrict__ out_hf) {
  int i = blockIdx.x; int t = threadIdx.x;
  if (t < HD) {
    float v;
    if (t < HID) {
      int p = *remain_step;
      int t2 = t & ~1;
      float div = expf(-(float)t2 * (logf(10000.f) / (float)HID));
      float ang = (float)p * div;
      float pe = (t & 1) ? cosf(ang) : sinf(ang);
      float hv = h[i * HID + t];
      out_h[i * HID + t] = hv;
      v = hv + pe;
    } else if (t < HID + 2) {
      v = x[i * 2 + (t - HID)];
    } else {
      v = label[i * KG + (t - HID - 2)];
    }
    hfull[i * HD + t] = v;
    out_hf[i * HD + t] = v;
  }
}

// C2: group means of h_full
__global__ __launch_bounds__(128) void k_gmean(
    const float* __restrict__ hfull, float* __restrict__ gmean) {
  int g = blockIdx.x; int t = threadIdx.x;
  if (t < HD) {
    float s = 0.f;
    for (int q = 0; q < MG; q++) s += hfull[(g * MG + q) * HD + t];
    gmean[g * HD + t] = s * 0.1f;
  }
}

// ---------------------------------------------------------------------------
// D: fused k_wsum + k_kv + k_B.
// ---------------------------------------------------------------------------
__global__ __launch_bounds__(256) void k_kvB(
    const float* __restrict__ hfull, const float* __restrict__ gmean,
    const float* __restrict__ w0, const float* __restrict__ b0v,
    const float* __restrict__ w1, const float* __restrict__ b1v,
    float* __restrict__ khfT, float* __restrict__ vhf,
    float* __restrict__ B1, float* __restrict__ B2) {
  int i = blockIdx.x; int t = threadIdx.x; int g = i / MG;
  __shared__ float hr[HD], gr[HD];
  if (t < HD) { hr[t] = hfull[i * HD + t]; gr[t] = gmean[g * HD + t]; }
  __syncthreads();
  for (int c = t; c < DM; c += 256) {
    const float* w0c = w0 + c;
    const float* w1c = w1 + c;
    float d0 = 0.f, d1 = 0.f, d2 = 0.f, d3 = 0.f;
    float g2 = 0.f, g3 = 0.f;
    float e0 = 0.f, e1 = 0.f, e2 = 0.f, e3 = 0.f;
    for (int dd = 0; dd < HD; dd++) {
      float hv = hr[dd], gv = gr[dd];
      float a0 = w0c[dd * DM];
      float a1 = w0c[(HD + dd) * DM];
      float a2 = w0c[(2 * HD + dd) * DM];
      float a3 = w0c[(3 * HD + dd) * DM];
      d0 += hv * a0; d1 += hv * a1; d2 += hv * a2; d3 += hv * a3;
      g2 += gv * a2; g3 += gv * a3;
      e0 += hv * w1c[dd * DM];
      e1 += hv * w1c[(HD + dd) * DM];
      e2 += hv * w1c[(2 * HD + dd) * DM];
      e3 += hv * w1c[(3 * HD + dd) * DM];
    }
    float b0c = b0v[c];
    khfT[c * NV + i] = b0c + d0 + d1 + d2 + d3;
    vhf[i * DM + c] = b1v[c] + e0 + e1 + e2 + e3;
    B1[i * DM + c] = d0 + g2;
    B2[i * DM + c] = b0c + d1 + g3;
  }
}

// D4: score components; khfT is [c][k] so the k-gather is coalesced.
__global__ __launch_bounds__(256) void k_SC(
    const float* __restrict__ B1, const float* __restrict__ B2,
    const float* __restrict__ khfT, float* __restrict__ SC1,
    float* __restrict__ SC2) {
  int i = blockIdx.x; int t = threadIdx.x;
  const float scl = 1.4426950408889634f / sqrtf((float)HD);
  __shared__ float b1r[DM], b2r[DM];
  for (int c = t; c < DM; c += 256) { b1r[c] = B1[i * DM + c]; b2r[c] = B2[i * DM + c]; }
  __syncthreads();
  for (int p = t; p < NH * NV; p += 256) {
    int h = p / NV, k = p - h * NV;
    float s1a = 0.f, s2a = 0.f;
    const float* kc = khfT + (size_t)h * HD * NV + k;
    const float* b1h = b1r + h * HD;
    const float* b2h = b2r + h * HD;
    for (int dd = 0; dd < HD; dd++) {
      float kv = kc[dd * NV];
      s1a += b1h[dd] * kv;
      s2a += b2h[dd] * kv;
    }
    SC1[h * NN + i * NV + k] = s1a * scl;
    SC2[h * NN + i * NV + k] = s2a * scl;
  }
}

// D5: softmax row constants C[h][i][j] = m + log2(l), coalesced row scans.
__global__ __launch_bounds__(256) void k_ml(
    const float* __restrict__ SC1, const float* __restrict__ SC2,
    float* __restrict__ C) {
  int i = blockIdx.x, h = blockIdx.y;
  int t = threadIdx.x;
  __shared__ float s1s[224];
  for (int k = t; k < 224; k += 256)
    s1s[k] = (k < NV) ? SC1[h * NN + i * NV + k] : -1e30f;
  __syncthreads();
  int l = t & 31;
  int g = t >> 5;
  const float* s2b = SC2 + h * NN;
  for (int it = 0; it < 25; ++it) {
    int j = it * 8 + g;
    const float* row = s2b + j * NV;
    float v[7];
#pragma unroll
    for (int e = 0; e < 7; ++e) {
      int k = l + 32 * e;
      v[e] = (k < NV) ? (s1s[k] + row[k]) : -1e30f;
    }
    float m = v[0];
#pragma unroll
    for (int e = 1; e < 7; ++e) m = fmaxf(m, v[e]);
#pragma unroll
    for (int off = 16; off > 0; off >>= 1) m = fmaxf(m, __shfl_xor(m, off, 32));
    float s = 0.f;
#pragma unroll
    for (int e = 0; e < 7; ++e) s += exp2f(v[e] - m);
#pragma unroll
    for (int off = 16; off > 0; off >>= 1) s += __shfl_xor(s, off, 32);
    if (l == 0) C[h * NN + i * NV + j] = m + log2f(s);
  }
}

// ---------------------------------------------------------------------------
// D6 (v8): row-normalized exponential tables, NODE-MAJOR layout [i][896]
// (heads side by side, matching ZT's flattened hk*32 k-offset).
// m1[h][i] = max_k SC1[h,i,k];  E1[i][h*224+k] = 2^(SC1-m1), 0 for k>=200.
// ---------------------------------------------------------------------------
__global__ __launch_bounds__(64) void k_E(
    const float* __restrict__ SC1, const float* __restrict__ SC2,
    float* __restrict__ E1, float* __restrict__ E2,
    float* __restrict__ M1, float* __restrict__ M2) {
  int i = blockIdx.x, h = blockIdx.y;
  int l = threadIdx.x;
  const float* s1 = SC1 + h * NN + i * NV;
  const float* s2 = SC2 + h * NN + i * NV;
  float v1[4], v2[4];
  float m1 = -1e30f, m2 = -1e30f;
#pragma unroll
  for (int e = 0; e < 4; ++e) {
    int k = l + 64 * e;
    if (k < NV) {
      v1[e] = s1[k]; v2[e] = s2[k];
      m1 = fmaxf(m1, v1[e]); m2 = fmaxf(m2, v2[e]);
    } else {
      v1[e] = -1e30f; v2[e] = -1e30f;
    }
  }
#pragma unroll
  for (int off = 32; off > 0; off >>= 1) {
    m1 = fmaxf(m1, __shfl_xor(m1, off));
    m2 = fmaxf(m2, __shfl_xor(m2, off));
  }
  float* d1 = E1 + (size_t)i * 896 + h * 224;
  float* d2 = E2 + (size_t)i * 896 + h * 224;
#pragma unroll
  for (int e = 0; e < 4; ++e) {
    int k = l + 64 * e;
    if (k < 224) {
      d1[k] = (k < NV) ? exp2f(v1[e] - m1) : 0.f;
      d2[k] = (k < NV) ? exp2f(v2[e] - m2) : 0.f;
    }
  }
  if (l == 0) { M1[h * NV + i] = m1; M2[h * NV + i] = m2; }
}

// ---------------------------------------------------------------------------
// E1: Z[h][k][c] = sum_d vhf[k][h*HD+d] * w3[(h*HD+d)*DM + c]  (fp32)
// ---------------------------------------------------------------------------
__global__ __launch_bounds__(256) void k_Z(
    const float* __restrict__ vhf, const float* __restrict__ w3,
    float* __restrict__ Z) {
  int k = blockIdx.x, h = blockIdx.y;
  int t = threadIdx.x;
  __shared__ float vr[HD];
  if (t < HD) vr[t] = vhf[k * DM + h * HD + t];
  __syncthreads();
  for (int c = t; c < DM; c += 256) {
    float a = 0.f;
    for (int d = 0; d < HD; ++d) a += vr[d] * w3[(h * HD + d) * DM + c];
    Z[((size_t)h * 224 + k) * DM + c] = a;
  }
}

// E2: ZT[c][h*224+kk] = bf16(Z[h][kk][c]) zero-padded. 512x896.
__global__ __launch_bounds__(256) void k_ZT(
    const float* __restrict__ Z, ushort* __restrict__ ZT) {
  int idx = blockIdx.x * 256 + threadIdx.x;  // < 512*896
  if (idx < 512 * 896) {
    int c = idx / 896, kp = idx - c * 896;
    int h = kp / 224, kk = kp - h * 224;
    ushort v = 0;
    if (c < DM && kk < NV) v = f2bf(Z[((size_t)h * 224 + kk) * DM + c]);
    ZT[idx] = v;
  }
}

// ---------------------------------------------------------------------------
// F (v8): fused GEMM, factored exponentials + v5 occupancy geometry +
// double-buffered B staging (ONE barrier per hk-step, was two).
//   P[p][hk] = si_h*E1[i][hk]*E2[j][hk] + sj_h*E1[j][hk]*E2[i][hk]
// Tile 64 rows x 128 cols, grid (4,315)=1260 blocks (~5/CU: the only
// geometry that reached 33% occupancy). Per hk-step: issue next B-tile
// loads -> A-gen (pure FMA) -> 8 MFMA from Bs[cur] -> write Bs[cur^1] ->
// barrier. 28 barriers total vs v5's 56; loads stay in flight across MFMA.
// ---------------------------------------------------------------------------
__global__ __launch_bounds__(256) void k_sfusedE2(
    const float* __restrict__ E1, const float* __restrict__ E2,
    const float* __restrict__ M1, const float* __restrict__ M2,
    const float* __restrict__ C, const ushort* __restrict__ ZT,
    const float* __restrict__ b3, float* __restrict__ outS) {
  int t = threadIdx.x;
  int c0 = blockIdx.x * 128, p0 = blockIdx.y * 64;
  int lane = t & 63, wm = t >> 6;
  int frow = lane & 15, quad = lane >> 4;
  __shared__ __align__(16) ushort Bs[2][128 * 40];
  int p = p0 + wm * 16 + frow;
  bool bval = (p < NT);
  int iA = 0, jA = 0;
  if (bval) p2ij(p, iA, jA);
  const float* e1i = E1 + (size_t)iA * 896;
  const float* e2i = E2 + (size_t)iA * 896;
  const float* e1j = E1 + (size_t)jA * 896;
  const float* e2j = E2 + (size_t)jA * 896;
  // per-head scale factors (8 exp2 total per thread, hoisted out of k-loop)
  float sih[NH], sjh[NH];
#pragma unroll
  for (int h = 0; h < NH; ++h) {
    float s1 = 0.f, s2 = 0.f;
    if (bval) {
      s1 = exp2f(M1[h * NV + iA] + M2[h * NV + jA] - C[h * NN + iA * NV + jA]);
      s2 = exp2f(M1[h * NV + jA] + M2[h * NV + iA] - C[h * NN + jA * NV + iA]);
    }
    sih[h] = s1; sjh[h] = s2;
  }
  float4v acc[8];
#pragma unroll
  for (int n = 0; n < 8; ++n) acc[n] = (float4v)(0.f);
  int rB = t >> 1, khB = (t & 1) * 16;
  // uint4 view of this thread's ZT row slot: row c0+rB, byte offset khB*2.
  const uint4* zrow = (const uint4*)(ZT + (size_t)(c0 + rB) * 896 + khB);
  // tile hk occupies zrow[hk*4] and zrow[hk*4+1] (32 ushorts = 4 uint4/row).

  // prologue: stage tile hk=0 into Bs[0]
  {
    uint4 q0 = zrow[0], q1 = zrow[1];
    *(uint4*)&Bs[0][rB * 40 + khB] = q0;
    *(uint4*)&Bs[0][rB * 40 + khB + 8] = q1;
  }
  __syncthreads();
#pragma unroll
  for (int h = 0; h < NH; ++h) {
#pragma unroll
    for (int ks = 0; ks < 7; ++ks) {
      const int hk = h * 7 + ks;
      const int cur = hk & 1;
      const int hkn = (hk < 27) ? hk + 1 : 27;  // clamp: last iter re-stages
      // --- issue next B-tile loads (in flight across A-gen + MFMA) ---
      uint4 nq0 = zrow[hkn * 4], nq1 = zrow[hkn * 4 + 1];
      // --- A fragment: pure FMA (no exp2, no branch; E zero-padded) ---
      int kb = hk * 32 + quad * 8;
      float4 A1 = *(const float4*)(e1i + kb), A1b = *(const float4*)(e1i + kb + 4);
      float4 B2 = *(const float4*)(e2j + kb), B2b = *(const float4*)(e2j + kb + 4);
      float4 D1 = *(const float4*)(e1j + kb), D1b = *(const float4*)(e1j + kb + 4);
      float4 E2v = *(const float4*)(e2i + kb), E2b = *(const float4*)(e2i + kb + 4);
      float si = sih[h], sj = sjh[h];
      float p0_ = si * (A1.x * B2.x) + sj * (D1.x * E2v.x);
      float p1_ = si * (A1.y * B2.y) + sj * (D1.y * E2v.y);
      float p2_ = si * (A1.z * B2.z) + sj * (D1.z * E2v.z);
      float p3_ = si * (A1.w * B2.w) + sj * (D1.w * E2v.w);
      float p4_ = si * (A1b.x * B2b.x) + sj * (D1b.x * E2b.x);
      float p5_ = si * (A1b.y * B2b.y) + sj * (D1b.y * E2b.y);
      float p6_ = si * (A1b.z * B2b.z) + sj * (D1b.z * E2b.z);
      float p7_ = si * (A1b.w * B2b.w) + sj * (D1b.w * E2b.w);
      union { uint4 q; short8v v; } af;
      af.q.x = packbf(p0_, p1_);
      af.q.y = packbf(p2_, p3_);
      af.q.z = packbf(p4_, p5_);
      af.q.w = packbf(p6_, p7_);
      // --- MFMA from current buffer (synced at end of previous step) ---
#pragma unroll
      for (int n = 0; n < 8; ++n) {
        short8v bf = *(const short8v*)&Bs[cur][(n * 16 + frow) * 40 + quad * 8];
        acc[n] = __builtin_amdgcn_mfma_f32_16x16x32_bf16(af.v, bf, acc[n],
                                                         0, 0, 0);
      }
      // --- stage next tile into the other buffer; single barrier ---
      *(uint4*)&Bs[cur ^ 1][rB * 40 + khB] = nq0;
      *(uint4*)&Bs[cur ^ 1][rB * 40 + khB + 8] = nq1;
      __syncthreads();
    }
  }
  // epilogue: C/D layout col=lane&15, row=quad*4+reg; mirror to (j,i).
  int ie[4], je[4];
#pragma unroll
  for (int r2 = 0; r2 < 4; ++r2) {
    int pe = p0 + wm * 16 + quad * 4 + r2;
    if (pe < NT) {
      p2ij(pe, ie[r2], je[r2]);
    } else {
      ie[r2] = -1; je[r2] = 0;
    }
  }
#pragma unroll
  for (int n = 0; n < 8; ++n) {
    int c = c0 + n * 16 + frow;
    if (c >= DM) continue;
    float bb = 2.0f * b3[c];
#pragma unroll
    for (int r2 = 0; r2 < 4; ++r2) {
      int ii = ie[r2];
      if (ii < 0) continue;
      int jj = je[r2];
      float v = acc[n][r2] + bb;
      outS[(size_t)(ii * NV + jj) * DM + c] = v;
      if (ii != jj) outS[(size_t)(jj * NV + ii) * DM + c] = v;
    }
  }
}

// ---------------------------------------------------------------------------
// G: Q_sa = relu(S@v1+b1)@v2 + b2, over unique (i<=j) rows; mirrored.
// ---------------------------------------------------------------------------
__global__ __launch_bounds__(256) void k_qsaT(
    const float* __restrict__ S, const float* __restrict__ v1w,
    const float* __restrict__ v1b, const float* __restrict__ v2w,
    const float* __restrict__ v2b, float* __restrict__ outQ) {
  __shared__ float Ss[64][9];
  __shared__ float V1s[8][48];
  __shared__ float Ts[64][49];
  __shared__ int rowI[64], rowJ[64];
  int t = threadIdx.x;
  int p0b = blockIdx.x * 64;
  if (t < 64) {
    int p = p0b + t;
    if (p < NT) {
      int ii, jj; p2ij(p, ii, jj);
      rowI[t] = ii; rowJ[t] = jj;
    } else {
      rowI[t] = -1; rowJ[t] = 0;
    }
  }
  int ty = t >> 4, tx = t & 15;
  int lr = t >> 2, lk = (t & 3) * 2;
  __syncthreads();
  int riS = rowI[lr];
  size_t srow = (riS >= 0) ? (size_t)(riS * NV + rowJ[lr]) * DM : 0;
  float acc[4][3];
#pragma unroll
  for (int y = 0; y < 4; y++)
#pragma unroll
    for (int xx = 0; xx < 3; xx++) acc[y][xx] = 0.f;
  for (int k0 = 0; k0 < DM; k0 += 8) {
    __syncthreads();
    Ss[lr][lk] = S[srow + k0 + lk];
    Ss[lr][lk + 1] = S[srow + k0 + lk + 1];
    if (t < 192) {
      int e = t * 2; int kk = e / 48, c = e - kk * 48;
      V1s[kk][c] = v1w[(k0 + kk) * 48 + c];
      V1s[kk][c + 1] = v1w[(k0 + kk) * 48 + c + 1];
    }
    __syncthreads();
#pragma unroll
    for (int kk = 0; kk < 8; kk++) {
      float a0 = Ss[ty * 4 + 0][kk], a1 = Ss[ty * 4 + 1][kk],
            a2 = Ss[ty * 4 + 2][kk], a3 = Ss[ty * 4 + 3][kk];
      float w0_ = V1s[kk][tx * 3 + 0], w1_ = V1s[kk][tx * 3 + 1],
            w2_ = V1s[kk][tx * 3 + 2];
      acc[0][0] += a0 * w0_; acc[0][1] += a0 * w1_; acc[0][2] += a0 * w2_;
      acc[1][0] += a1 * w0_; acc[1][1] += a1 * w1_; acc[1][2] += a1 * w2_;
      acc[2][0] += a2 * w0_; acc[2][1] += a2 * w1_; acc[2][2] += a2 * w2_;
      acc[3][0] += a3 * w0_; acc[3][1] += a3 * w1_; acc[3][2] += a3 * w2_;
    }
  }
#pragma unroll
  for (int y = 0; y < 4; y++)
#pragma unroll
    for (int xx = 0; xx < 3; xx++)
      Ts[ty * 4 + y][tx * 3 + xx] = fmaxf(acc[y][xx] + v1b[tx * 3 + xx], 0.f);
  __syncthreads();
  if (t < 64 && rowI[t] >= 0) {
    float q = v2b[0];
    for (int c = 0; c < 48; c++) q += Ts[t][c] * v2w[c];
    int ii = rowI[t], jj = rowJ[t];
    outQ[ii * NV + jj] = q;
    if (ii != jj) outQ[jj * NV + ii] = q;
  }
}

// ---------------------------------------------------------------------------
extern "C" void kernel_launch(void* const* d_in, const int* in_sizes, int n_in,
                              void* d_out, int out_size, void* d_ws,
                              size_t ws_size, hipStream_t stream) {
  const float* x = (const float*)d_in[0];
  const float* label = (const float*)d_in[1];
  const float* h0 = (const float*)d_in[2];
  const float* w = (const float*)d_in[3];
  const float* dmat = (const float*)d_in[4];
  const float* l0w = (const float*)d_in[5];
  const float* l0b = (const float*)d_in[6];
  const float* l1w = (const float*)d_in[7];
  const float* l1b = (const float*)d_in[8];
  const float* l2w = (const float*)d_in[9];
  const float* l2b = (const float*)d_in[10];
  const float* l3w = (const float*)d_in[11];
  const float* l3b = (const float*)d_in[12];
  const float* l4w = (const float*)d_in[13];
  const float* l4b = (const float*)d_in[14];
  const float* l5w = (const float*)d_in[15];
  const float* l5b = (const float*)d_in[16];
  const float* w0 = (const float*)d_in[17];
  const float* b0v = (const float*)d_in[18];
  const float* w1 = (const float*)d_in[19];
  const float* b1v = (const float*)d_in[20];
  const float* w3 = (const float*)d_in[21];
  const float* b3 = (const float*)d_in[22];
  const float* v1w = (const float*)d_in[23];
  const float* v1b = (const float*)d_in[24];
  const float* v2w = (const float*)d_in[25];
  const float* v2b = (const float*)d_in[26];
  const int* remain_step = (const int*)d_in[29];

  float* ws = (float*)d_ws;
  float* base = ws + WS_BASE;
  float* h1 = ws + WS_H1;
  float* h2 = ws + WS_H2;
  float* hfull = ws + WS_HFULL;
  float* gmean = ws + WS_GMEAN;
  float* khfT = ws + WS_KHF;
  float* vhf = ws + WS_VHF;
  float* B1 = ws + WS_B1;
  float* B2 = ws + WS_B2;
  float* SC1 = ws + WS_SC1;
  float* SC2 = ws + WS_SC2;
  float* Z = ws + WS_Z;
  ushort* ZT = (ushort*)(ws + WS_ZT);
  float* E1 = ws + WS_E1;
  float* E2 = ws + WS_E2;
  float* M1 = ws + WS_M1;
  float* M2 = ws + WS_M2;
  float* C = ws + WS_B1;  // reuses B1/B2 slots after k_SC

  float* outS = (float*)d_out;
  float* outH = outS + OFF_H;
  float* outHF = outS + OFF_HF;
  float* outQ = outS + OFF_Q;

  k_base<<<NV, 256, 0, stream>>>(x, dmat, label, l0w, l0b, l1w, l1b, l2b, l3b,
                                 l4w, l4b, l5w, l5b, base);
  k_gcn<<<NV, 192, 0, stream>>>(h0, base, w, l2w, l3w, h1);
  k_gcn<<<NV, 192, 0, stream>>>(h1, base, w, l2w, l3w, h2);
  k_hfull<<<NV, 128, 0, stream>>>(h2, x, label, remain_step, hfull, outH, outHF);
  k_gmean<<<KG, 128, 0, stream>>>(hfull, gmean);
  k_kvB<<<NV, 256, 0, stream>>>(hfull, gmean, w0, b0v, w1, b1v, khfT, vhf, B1,
                                B2);
  k_Z<<<dim3(NV, NH), 256, 0, stream>>>(vhf, w3, Z);
  k_ZT<<<(512 * 896 + 255) / 256, 256, 0, stream>>>(Z, ZT);
  k_SC<<<NV, 256, 0, stream>>>(B1, B2, khfT, SC1, SC2);
  k_ml<<<dim3(NV, NH), 256, 0, stream>>>(SC1, SC2, C);
  k_E<<<dim3(NV, NH), 64, 0, stream>>>(SC1, SC2, E1, E2, M1, M2);
  k_sfusedE2<<<dim3(4, NTP / 64), 256, 0, stream>>>(E1, E2, M1, M2, C, ZT, b3,
                                                    outS);
  k_qsaT<<<(NT + 63) / 64, 256, 0, stream>>>(outS, v1w, v1b, v2w, v2b, outQ);
}

// Round 8
// 592.644 us; speedup vs baseline: 1.0934x; 1.0764x over previous
//
#include <hip/hip_runtime.h>
#include <hip/hip_bf16.h>
#include <math.h>

typedef unsigned short ushort;
typedef unsigned int uint;

// Sizes (fixed by the reference problem)
#define NV 200     // N nodes
#define DEG 199
#define HID 96
#define KG 20      // groups / one-hot width
#define MG 10      // group size
#define AJR 30
#define NH 4
#define HD 118     // HID + 2 + K
#define DM 472     // NH*HD
#define NN 40000   // N*N
#define NT 20100   // N*(N+1)/2 unique (i<=j) pairs: S[(i,j)] == S[(j,i)]
#define NTP 20160  // NT rounded up to 64 (315 blocks * 64 rows)

// Workspace layout (float units).
#define WS_BASE   0
#define WS_H1     19200
#define WS_H2     38400
#define WS_HFULL  57600
#define WS_GMEAN  81200
#define WS_KHF    194952   // khfT [DM][NV] = 94400 floats (transposed!)
#define WS_VHF    289352
#define WS_B1     383752   // after k_SC: reused for C (softmax row consts)
#define WS_B2     478152
#define WS_SC1    572552
#define WS_SC2    732552
#define WS_Z      892552             // Z fp32: 4*224*472 = 422,912 floats
#define WS_ZT     1315464            // ZT bf16: 512*896 ushorts = 229,376 floats
#define WS_TP     1544840            // Tpart fp32 [4][NTP][48] = 3,870,720 floats
// end = 5,415,560 floats = 21.7 MB; ws_size >= 42.3 MB proven by round-5 run.

// Output layout (floats)
#define OFF_H   18880000
#define OFF_HF  18899200
#define OFF_Q   18922800

typedef __attribute__((ext_vector_type(8))) short short8v;
typedef __attribute__((ext_vector_type(4))) float float4v;

__device__ __forceinline__ float bf2f(uint u) {
  return __uint_as_float(u << 16);
}
__device__ __forceinline__ ushort f2bf(float f) {
  uint u = __float_as_uint(f);
  uint r = (u + 0x7fffu + ((u >> 16) & 1u)) >> 16;  // RNE
  return (ushort)r;
}
__device__ __forceinline__ uint packbf(float a, float b) {
  __hip_bfloat162 h2 = __float22bfloat162_rn(make_float2(a, b));
  union { __hip_bfloat162 h; uint u; } c;
  c.h = h2;
  return c.u;
}

// Packed upper-triangle index p (0..NT-1) -> (i,j), i<=j.
__device__ __forceinline__ int triOff(int i) {
  return i * 200 - ((i * (i - 1)) >> 1);
}
__device__ __forceinline__ void p2ij(int p, int& io, int& jo) {
  float s = sqrtf((float)(160801 - 8 * p));   // (2N+1)^2 - 8p
  int i = (int)((401.0f - s) * 0.5f);
  if (i < 0) i = 0;
  if (i > 199) i = 199;
  while (i > 0 && triOff(i) > p) --i;
  while (i < 199 && triOff(i + 1) <= p) ++i;
  io = i;
  jo = i + (p - triOff(i));
}

// ---------------------------------------------------------------------------
// A: iteration-invariant part of the GCN update
// ---------------------------------------------------------------------------
__global__ __launch_bounds__(256) void k_base(
    const float* __restrict__ x, const float* __restrict__ dmat,
    const float* __restrict__ label,
    const float* __restrict__ l0w, const float* __restrict__ l0b,
    const float* __restrict__ l1w, const float* __restrict__ l1b,
    const float* __restrict__ l2b, const float* __restrict__ l3b,
    const float* __restrict__ l4w, const float* __restrict__ l4b,
    const float* __restrict__ l5w, const float* __restrict__ l5b,
    float* __restrict__ base) {
  int i = blockIdx.x; int t = threadIdx.x;
  int g = i / MG;
  __shared__ float sv[256];
  __shared__ float sn2[9];
  float v = -1.0f;
  if (t < DEG) {
    int u = (t < i) ? t : t + 1;
    if (u / MG != g) v = dmat[i * DEG + t];
  }
  sv[t] = v;
  __syncthreads();
  for (int k2 = 2; k2 <= 256; k2 <<= 1) {
    for (int jj = k2 >> 1; jj > 0; jj >>= 1) {
      int ixj = t ^ jj;
      if (ixj > t) {
        float a = sv[t], b = sv[ixj];
        bool sw = ((t & k2) == 0) ? (a < b) : (a > b);
        if (sw) { sv[t] = b; sv[ixj] = a; }
      }
      __syncthreads();
    }
  }
  if (t == 0) {
    float tmp[9];
    for (int q = 0; q < 9; q++) tmp[q] = dmat[i * DEG + MG * g + q];
    for (int a2 = 1; a2 < 9; a2++) {
      float key = tmp[a2]; int b2 = a2 - 1;
      while (b2 >= 0 && tmp[b2] < key) { tmp[b2 + 1] = tmp[b2]; b2--; }
      tmp[b2 + 1] = key;
    }
    for (int q = 0; q < 9; q++) sn2[q] = tmp[q];
  }
  __syncthreads();
  if (t < HID) {
    float acc = l0b[t] + l1b[t] + l2b[t] + l3b[t] + l4b[t] + l5b[t];
    acc += x[i * 2 + 0] * l0w[t] + x[i * 2 + 1] * l0w[HID + t];
    for (int k = 0; k < KG; k++) acc += label[i * KG + k] * l1w[k * HID + t];
    for (int q = 0; q < AJR; q++) acc += sv[q] * l4w[q * HID + t];
    for (int q = 0; q < 9; q++) acc += sn2[q] * l5w[q * HID + t];
    base[i * HID + t] = acc;
  }
}

// ---------------------------------------------------------------------------
// B: one GCN step
// ---------------------------------------------------------------------------
__global__ __launch_bounds__(192) void k_gcn(
    const float* __restrict__ hin, const float* __restrict__ base,
    const float* __restrict__ w, const float* __restrict__ l2w,
    const float* __restrict__ l3w, float* __restrict__ hout) {
  int i = blockIdx.x; int t = threadIdx.x;
  int g = i / MG;
  __shared__ float n1[HID], n2[HID];
  if (t < HID) {
    float acc = 0.f, wsum = 0.f;
    for (int j = 0; j < DEG; j++) {
      int u = (j < i) ? j : j + 1;
      if (u / MG != g) {
        float wj = w[i * DEG + j];
        acc += wj * hin[u * HID + t];
        wsum += wj;
      }
    }
    n1[t] = acc / wsum;
  } else if (t < 2 * HID) {
    int dd = t - HID;
    float acc = 0.f, wsum = 0.f;
    for (int u = MG * g; u < MG * g + MG; u++) {
      if (u == i) continue;
      int j = (u < i) ? u : u - 1;
      float wj = w[i * DEG + j];
      acc += wj * hin[u * HID + dd];
      wsum += wj;
    }
    n2[dd] = acc / wsum;
  }
  __syncthreads();
  if (t < HID) {
    float acc = base[i * HID + t];
    for (int dd = 0; dd < HID; dd++)
      acc += n1[dd] * l2w[dd * HID + t] + n2[dd] * l3w[dd * HID + t];
    hout[i * HID + t] = fmaxf(acc, 0.f);
  }
}

// ---------------------------------------------------------------------------
// C1: h_full assembly (+ h, h_full outputs)
// ---------------------------------------------------------------------------
__global__ __launch_bounds__(128) void k_hfull(
    const float* __restrict__ h, const float* __restrict__ x,
    const float* __restrict__ label, const int* __restrict__ remain_step,
    float* __restrict__ hfull, float* __restrict__ out_h,
    float* __restrict__ out_hf) {
  int i = blockIdx.x; int t = threadIdx.x;
  if (t < HD) {
    float v;
    if (t < HID) {
      int p = *remain_step;
      int t2 = t & ~1;
      float div = expf(-(float)t2 * (logf(10000.f) / (float)HID));
      float ang = (float)p * div;
      float pe = (t & 1) ? cosf(ang) : sinf(ang);
      float hv = h[i * HID + t];
      out_h[i * HID + t] = hv;
      v = hv + pe;
    } else if (t < HID + 2) {
      v = x[i * 2 + (t - HID)];
    } else {
      v = label[i * KG + (t - HID - 2)];
    }
    hfull[i * HD + t] = v;
    out_hf[i * HD + t] = v;
  }
}

// C2: group means of h_full
__global__ __launch_bounds__(128) void k_gmean(
    const float* __restrict__ hfull, float* __restrict__ gmean) {
  int g = blockIdx.x; int t = threadIdx.x;
  if (t < HD) {
    float s = 0.f;
    for (int q = 0; q < MG; q++) s += hfull[(g * MG + q) * HD + t];
    gmean[g * HD + t] = s * 0.1f;
  }
}

// ---------------------------------------------------------------------------
// D: fused k_wsum + k_kv + k_B.
//   khfT[c][i] = b0v[c] + d0+d1+d2+d3        (khf TRANSPOSED for k_SC reads)
//   vhf[i][c]  = b1v[c] + e0+e1+e2+e3
//   B1[i][c]   = d0 + g2
//   B2[i][c]   = b0v[c] + d1 + g3
// ---------------------------------------------------------------------------
__global__ __launch_bounds__(256) void k_kvB(
    const float* __restrict__ hfull, const float* __restrict__ gmean,
    const float* __restrict__ w0, const float* __restrict__ b0v,
    const float* __restrict__ w1, const float* __restrict__ b1v,
    float* __restrict__ khfT, float* __restrict__ vhf,
    float* __restrict__ B1, float* __restrict__ B2) {
  int i = blockIdx.x; int t = threadIdx.x; int g = i / MG;
  __shared__ float hr[HD], gr[HD];
  if (t < HD) { hr[t] = hfull[i * HD + t]; gr[t] = gmean[g * HD + t]; }
  __syncthreads();
  for (int c = t; c < DM; c += 256) {
    const float* w0c = w0 + c;
    const float* w1c = w1 + c;
    float d0 = 0.f, d1 = 0.f, d2 = 0.f, d3 = 0.f;
    float g2 = 0.f, g3 = 0.f;
    float e0 = 0.f, e1 = 0.f, e2 = 0.f, e3 = 0.f;
    for (int dd = 0; dd < HD; dd++) {
      float hv = hr[dd], gv = gr[dd];
      float a0 = w0c[dd * DM];
      float a1 = w0c[(HD + dd) * DM];
      float a2 = w0c[(2 * HD + dd) * DM];
      float a3 = w0c[(3 * HD + dd) * DM];
      d0 += hv * a0; d1 += hv * a1; d2 += hv * a2; d3 += hv * a3;
      g2 += gv * a2; g3 += gv * a3;
      e0 += hv * w1c[dd * DM];
      e1 += hv * w1c[(HD + dd) * DM];
      e2 += hv * w1c[(2 * HD + dd) * DM];
      e3 += hv * w1c[(3 * HD + dd) * DM];
    }
    float b0c = b0v[c];
    khfT[c * NV + i] = b0c + d0 + d1 + d2 + d3;
    vhf[i * DM + c] = b1v[c] + e0 + e1 + e2 + e3;
    B1[i * DM + c] = d0 + g2;
    B2[i * DM + c] = b0c + d1 + g3;
  }
}

// D4: score components; khfT is [c][k] so the k-gather is coalesced.
__global__ __launch_bounds__(256) void k_SC(
    const float* __restrict__ B1, const float* __restrict__ B2,
    const float* __restrict__ khfT, float* __restrict__ SC1,
    float* __restrict__ SC2) {
  int i = blockIdx.x; int t = threadIdx.x;
  const float scl = 1.4426950408889634f / sqrtf((float)HD);
  __shared__ float b1r[DM], b2r[DM];
  for (int c = t; c < DM; c += 256) { b1r[c] = B1[i * DM + c]; b2r[c] = B2[i * DM + c]; }
  __syncthreads();
  for (int p = t; p < NH * NV; p += 256) {
    int h = p / NV, k = p - h * NV;
    float s1a = 0.f, s2a = 0.f;
    const float* kc = khfT + (size_t)h * HD * NV + k;
    const float* b1h = b1r + h * HD;
    const float* b2h = b2r + h * HD;
    for (int dd = 0; dd < HD; dd++) {
      float kv = kc[dd * NV];
      s1a += b1h[dd] * kv;
      s2a += b2h[dd] * kv;
    }
    SC1[h * NN + i * NV + k] = s1a * scl;
    SC2[h * NN + i * NV + k] = s2a * scl;
  }
}

// D5: softmax row constants C[h][i][j] = m + log2(l), coalesced row scans.
__global__ __launch_bounds__(256) void k_ml(
    const float* __restrict__ SC1, const float* __restrict__ SC2,
    float* __restrict__ C) {
  int i = blockIdx.x, h = blockIdx.y;
  int t = threadIdx.x;
  __shared__ float s1s[224];
  for (int k = t; k < 224; k += 256)
    s1s[k] = (k < NV) ? SC1[h * NN + i * NV + k] : -1e30f;
  __syncthreads();
  int l = t & 31;
  int g = t >> 5;
  const float* s2b = SC2 + h * NN;
  for (int it = 0; it < 25; ++it) {
    int j = it * 8 + g;
    const float* row = s2b + j * NV;
    float v[7];
#pragma unroll
    for (int e = 0; e < 7; ++e) {
      int k = l + 32 * e;
      v[e] = (k < NV) ? (s1s[k] + row[k]) : -1e30f;
    }
    float m = v[0];
#pragma unroll
    for (int e = 1; e < 7; ++e) m = fmaxf(m, v[e]);
#pragma unroll
    for (int off = 16; off > 0; off >>= 1) m = fmaxf(m, __shfl_xor(m, off, 32));
    float s = 0.f;
#pragma unroll
    for (int e = 0; e < 7; ++e) s += exp2f(v[e] - m);
#pragma unroll
    for (int off = 16; off > 0; off >>= 1) s += __shfl_xor(s, off, 32);
    if (l == 0) C[h * NN + i * NV + j] = m + log2f(s);
  }
}

// ---------------------------------------------------------------------------
// E1: Z[h][k][c] = sum_d vhf[k][h*HD+d] * w3[(h*HD+d)*DM + c]  (fp32)
// ---------------------------------------------------------------------------
__global__ __launch_bounds__(256) void k_Z(
    const float* __restrict__ vhf, const float* __restrict__ w3,
    float* __restrict__ Z) {
  int k = blockIdx.x, h = blockIdx.y;
  int t = threadIdx.x;
  __shared__ float vr[HD];
  if (t < HD) vr[t] = vhf[k * DM + h * HD + t];
  __syncthreads();
  for (int c = t; c < DM; c += 256) {
    float a = 0.f;
    for (int d = 0; d < HD; ++d) a += vr[d] * w3[(h * HD + d) * DM + c];
    Z[((size_t)h * 224 + k) * DM + c] = a;
  }
}

// E2: ZT[c][h*224+kk] = bf16(Z[h][kk][c]) zero-padded. 512x896.
__global__ __launch_bounds__(256) void k_ZT(
    const float* __restrict__ Z, ushort* __restrict__ ZT) {
  int idx = blockIdx.x * 256 + threadIdx.x;  // < 512*896
  if (idx < 512 * 896) {
    int c = idx / 896, kp = idx - c * 896;
    int h = kp / 224, kk = kp - h * 224;
    ushort v = 0;
    if (c < DM && kk < NV) v = f2bf(Z[((size_t)h * 224 + kk) * DM + c]);
    ZT[idx] = v;
  }
}

// ---------------------------------------------------------------------------
// F (v9): round-4's proven k_sfusedT2 main loop (110 us, best measured),
// plus a fused epilogue computing the v1-projection partials
//   Tpart[tile][p][q] = sum_{c in tile} S[p][c] * v1w[c][q]   (q = 0..47)
// from the in-register S-tile (staged 32 rows at a time through 17 KB LDS).
// This removes k_qsaT's 75.5 MB re-read of S; a tiny k_qred finishes Q_sa.
// Tile 64 packed rows x 128 cols, grid (4, 315) = 1260 blocks.
// ---------------------------------------------------------------------------
__global__ __launch_bounds__(256) void k_sfusedTQ(
    const float* __restrict__ SC1, const float* __restrict__ SC2,
    const float* __restrict__ C, const ushort* __restrict__ ZT,
    const float* __restrict__ b3, const float* __restrict__ v1w,
    float* __restrict__ outS, float* __restrict__ Tp) {
  int t = threadIdx.x;
  int c0 = blockIdx.x * 128, p0 = blockIdx.y * 64;
  int lane = t & 63, wm = t >> 6;
  int frow = lane & 15, quad = lane >> 4;
  __shared__ __align__(16) ushort Bs[128 * 40];
  __shared__ float Sl[128][33];   // 32-row S panel for the epilogue GEMM
  // this lane's A-frag row (packed index)
  int p = p0 + wm * 16 + frow;
  bool bval = (p < NT);
  int iA = 0, jA = 0;
  if (bval) p2ij(p, iA, jA);
  int iN = iA * NV, jN = jA * NV;
  float4v acc[8];
#pragma unroll
  for (int n = 0; n < 8; ++n) acc[n] = (float4v)(0.f);
  int rB = t >> 1, khB = (t & 1) * 16;

  for (int h = 0; h < NH; ++h) {
    int hb = h * NN;
    const float* s1h = SC1 + hb;
    const float* s2h = SC2 + hb;
    float ci = bval ? C[hb + iN + jA] : 0.f;
    float cj = bval ? C[hb + jN + iA] : 0.f;
    for (int ks = 0; ks < 7; ++ks) {
      int kb = ks * 32 + quad * 8;
      bool kvalid = (kb + 7 < NV);
      // --- generate A fragment in-register ---
      union { uint4 q; short8v v; } af;
      if (bval && kvalid) {
        const float* q1i = s1h + iN + kb;
        const float* q2i = s2h + iN + kb;
        const float* q1j = s1h + jN + kb;
        const float* q2j = s2h + jN + kb;
        float4 a0 = *(const float4*)q1i,   a0b = *(const float4*)(q1i + 4);
        float4 b0 = *(const float4*)q2j,   b0b = *(const float4*)(q2j + 4);
        float4 d0 = *(const float4*)q1j,   d0b = *(const float4*)(q1j + 4);
        float4 e0 = *(const float4*)q2i,   e0b = *(const float4*)(q2i + 4);
        float p0_ = exp2f(a0.x + b0.x - ci) + exp2f(d0.x + e0.x - cj);
        float p1_ = exp2f(a0.y + b0.y - ci) + exp2f(d0.y + e0.y - cj);
        float p2_ = exp2f(a0.z + b0.z - ci) + exp2f(d0.z + e0.z - cj);
        float p3_ = exp2f(a0.w + b0.w - ci) + exp2f(d0.w + e0.w - cj);
        float p4_ = exp2f(a0b.x + b0b.x - ci) + exp2f(d0b.x + e0b.x - cj);
        float p5_ = exp2f(a0b.y + b0b.y - ci) + exp2f(d0b.y + e0b.y - cj);
        float p6_ = exp2f(a0b.z + b0b.z - ci) + exp2f(d0b.z + e0b.z - cj);
        float p7_ = exp2f(a0b.w + b0b.w - ci) + exp2f(d0b.w + e0b.w - cj);
        af.q.x = packbf(p0_, p1_);
        af.q.y = packbf(p2_, p3_);
        af.q.z = packbf(p4_, p5_);
        af.q.w = packbf(p6_, p7_);
      } else {
        af.q = make_uint4(0, 0, 0, 0);
      }
      // --- stage B tile (Z^T slice) ---
      const uint4* wp = (const uint4*)(ZT + (size_t)(c0 + rB) * 896 +
                                       h * 224 + ks * 32 + khB);
      uint4 bq0 = wp[0], bq1 = wp[1];
      __syncthreads();
      *(uint4*)&Bs[rB * 40 + khB] = bq0;
      *(uint4*)&Bs[rB * 40 + khB + 8] = bq1;
      __syncthreads();
      // --- MFMA ---
#pragma unroll
      for (int n = 0; n < 8; ++n) {
        short8v bf = *(const short8v*)&Bs[(n * 16 + frow) * 40 + quad * 8];
        acc[n] = __builtin_amdgcn_mfma_f32_16x16x32_bf16(af.v, bf, acc[n],
                                                         0, 0, 0);
      }
    }
  }
  // epilogue 1: S writes, C/D layout col=lane&15, row=quad*4+reg; mirrored.
  int ie[4], je[4];
#pragma unroll
  for (int r2 = 0; r2 < 4; ++r2) {
    int pe = p0 + wm * 16 + quad * 4 + r2;
    if (pe < NT) {
      p2ij(pe, ie[r2], je[r2]);
    } else {
      ie[r2] = -1; je[r2] = 0;
    }
  }
#pragma unroll
  for (int n = 0; n < 8; ++n) {
    int c = c0 + n * 16 + frow;
    if (c >= DM) continue;
    float bb = 2.0f * b3[c];
#pragma unroll
    for (int r2 = 0; r2 < 4; ++r2) {
      int ii = ie[r2];
      if (ii < 0) continue;
      int jj = je[r2];
      float v = acc[n][r2] + bb;
      outS[(size_t)(ii * NV + jj) * DM + c] = v;
      if (ii != jj) outS[(size_t)(jj * NV + ii) * DM + c] = v;
    }
  }
  // epilogue 2: fused v1-projection partials (replaces k_qsaT's big GEMM).
  // Two passes of 32 rows: waves 2p,2p+1 own the rows of pass p.
  int cmax = DM - c0; if (cmax > 128) cmax = 128;  // skip zero cols (bx=3)
  int lrow = t >> 3;          // 0..31: row within pass
  int qg = (t & 7) * 6;       // 6 q-outputs per thread
#pragma unroll
  for (int pass = 0; pass < 2; ++pass) {
    __syncthreads();          // previous pass's Sl reads complete
    if ((wm >> 1) == pass) {
      int lr = (wm & 1) * 16 + quad * 4;
#pragma unroll
      for (int n = 0; n < 8; ++n) {
        int c = c0 + n * 16 + frow;
        bool cv = (c < DM);
        float bb = cv ? 2.0f * b3[c] : 0.f;
#pragma unroll
        for (int r2 = 0; r2 < 4; ++r2)
          Sl[n * 16 + frow][lr + r2] = cv ? (acc[n][r2] + bb) : 0.f;
      }
    }
    __syncthreads();
    float ta0 = 0.f, ta1 = 0.f, ta2 = 0.f, ta3 = 0.f, ta4 = 0.f, ta5 = 0.f;
    for (int col = 0; col < cmax; ++col) {
      float s = Sl[col][lrow];
      const float* vw = v1w + (size_t)(c0 + col) * 48 + qg;
      ta0 += s * vw[0]; ta1 += s * vw[1]; ta2 += s * vw[2];
      ta3 += s * vw[3]; ta4 += s * vw[4]; ta5 += s * vw[5];
    }
    float* tp = Tp + ((size_t)blockIdx.x * NTP + p0 + pass * 32 + lrow) * 48 + qg;
    tp[0] = ta0; tp[1] = ta1; tp[2] = ta2;
    tp[3] = ta3; tp[4] = ta4; tp[5] = ta5;
  }
}

// ---------------------------------------------------------------------------
// G (v9): Q_sa finish: sum 4 tile-partials + v1b -> relu -> dot v2w + v2b.
// Reads 15.5 MB (vs k_qsaT's 75.5 MB S re-read). Mirror write.
// ---------------------------------------------------------------------------
__global__ __launch_bounds__(256) void k_qred(
    const float* __restrict__ Tp, const float* __restrict__ v1b,
    const float* __restrict__ v2w, const float* __restrict__ v2b,
    float* __restrict__ outQ) {
  int p = blockIdx.x * 256 + threadIdx.x;
  if (p >= NT) return;
  const float* t0 = Tp + (size_t)p * 48;
  const float* t1 = t0 + (size_t)NTP * 48;
  const float* t2 = t1 + (size_t)NTP * 48;
  const float* t3 = t2 + (size_t)NTP * 48;
  float q = v2b[0];
#pragma unroll 8
  for (int e = 0; e < 48; ++e) {
    float tv = t0[e] + t1[e] + t2[e] + t3[e] + v1b[e];
    q += fmaxf(tv, 0.f) * v2w[e];
  }
  int ii, jj;
  p2ij(p, ii, jj);
  outQ[ii * NV + jj] = q;
  if (ii != jj) outQ[jj * NV + ii] = q;
}

// ---------------------------------------------------------------------------
extern "C" void kernel_launch(void* const* d_in, const int* in_sizes, int n_in,
                              void* d_out, int out_size, void* d_ws,
                              size_t ws_size, hipStream_t stream) {
  const float* x = (const float*)d_in[0];
  const float* label = (const float*)d_in[1];
  const float* h0 = (const float*)d_in[2];
  const float* w = (const float*)d_in[3];
  const float* dmat = (const float*)d_in[4];
  const float* l0w = (const float*)d_in[5];
  const float* l0b = (const float*)d_in[6];
  const float* l1w = (const float*)d_in[7];
  const float* l1b = (const float*)d_in[8];
  const float* l2w = (const float*)d_in[9];
  const float* l2b = (const float*)d_in[10];
  const float* l3w = (const float*)d_in[11];
  const float* l3b = (const float*)d_in[12];
  const float* l4w = (const float*)d_in[13];
  const float* l4b = (const float*)d_in[14];
  const float* l5w = (const float*)d_in[15];
  const float* l5b = (const float*)d_in[16];
  const float* w0 = (const float*)d_in[17];
  const float* b0v = (const float*)d_in[18];
  const float* w1 = (const float*)d_in[19];
  const float* b1v = (const float*)d_in[20];
  const float* w3 = (const float*)d_in[21];
  const float* b3 = (const float*)d_in[22];
  const float* v1w = (const float*)d_in[23];
  const float* v1b = (const float*)d_in[24];
  const float* v2w = (const float*)d_in[25];
  const float* v2b = (const float*)d_in[26];
  const int* remain_step = (const int*)d_in[29];

  float* ws = (float*)d_ws;
  float* base = ws + WS_BASE;
  float* h1 = ws + WS_H1;
  float* h2 = ws + WS_H2;
  float* hfull = ws + WS_HFULL;
  float* gmean = ws + WS_GMEAN;
  float* khfT = ws + WS_KHF;
  float* vhf = ws + WS_VHF;
  float* B1 = ws + WS_B1;
  float* B2 = ws + WS_B2;
  float* SC1 = ws + WS_SC1;
  float* SC2 = ws + WS_SC2;
  float* Z = ws + WS_Z;
  ushort* ZT = (ushort*)(ws + WS_ZT);
  float* Tp = ws + WS_TP;
  float* C = ws + WS_B1;  // reuses B1/B2 slots after k_SC

  float* outS = (float*)d_out;
  float* outH = outS + OFF_H;
  float* outHF = outS + OFF_HF;
  float* outQ = outS + OFF_Q;

  k_base<<<NV, 256, 0, stream>>>(x, dmat, label, l0w, l0b, l1w, l1b, l2b, l3b,
                                 l4w, l4b, l5w, l5b, base);
  k_gcn<<<NV, 192, 0, stream>>>(h0, base, w, l2w, l3w, h1);
  k_gcn<<<NV, 192, 0, stream>>>(h1, base, w, l2w, l3w, h2);
  k_hfull<<<NV, 128, 0, stream>>>(h2, x, label, remain_step, hfull, outH, outHF);
  k_gmean<<<KG, 128, 0, stream>>>(hfull, gmean);
  k_kvB<<<NV, 256, 0, stream>>>(hfull, gmean, w0, b0v, w1, b1v, khfT, vhf, B1,
                                B2);
  k_Z<<<dim3(NV, NH), 256, 0, stream>>>(vhf, w3, Z);
  k_ZT<<<(512 * 896 + 255) / 256, 256, 0, stream>>>(Z, ZT);
  k_SC<<<NV, 256, 0, stream>>>(B1, B2, khfT, SC1, SC2);
  k_ml<<<dim3(NV, NH), 256, 0, stream>>>(SC1, SC2, C);
  k_sfusedTQ<<<dim3(4, NTP / 64), 256, 0, stream>>>(SC1, SC2, C, ZT, b3, v1w,
                                                    outS, Tp);
  k_qred<<<(NT + 255) / 256, 256, 0, stream>>>(Tp, v1b, v2w, v2b, outQ);
}

// Round 9
// 507.319 us; speedup vs baseline: 1.2773x; 1.1682x over previous
//
#include <hip/hip_runtime.h>
#include <hip/hip_bf16.h>
#include <math.h>

typedef unsigned short ushort;
typedef unsigned int uint;

// Sizes (fixed by the reference problem)
#define NV 200     // N nodes
#define DEG 199
#define HID 96
#define KG 20      // groups / one-hot width
#define MG 10      // group size
#define AJR 30
#define NH 4
#define HD 118     // HID + 2 + K
#define DM 472     // NH*HD
#define NN 40000   // N*N
#define NT 20100   // N*(N+1)/2 unique (i<=j) pairs: S[(i,j)] == S[(j,i)]
#define NTP 20160  // NT rounded up to 64

// Workspace layout (float units).
#define WS_BASE   0
#define WS_H1     19200
#define WS_H2     38400
#define WS_HFULL  57600
#define WS_GMEAN  81200
#define WS_KHF    194952   // khfT [DM][NV] = 94400 floats (transposed!)
#define WS_VHF    289352
#define WS_B1     383752   // after k_SC: reused for C (softmax row consts)
#define WS_B2     478152
#define WS_SC1    572552
#define WS_SC2    732552
#define WS_ZT     1315464  // ZT bf16: 512*896 ushorts = 229,376 floats

// Output layout (floats)
#define OFF_H   18880000
#define OFF_HF  18899200
#define OFF_Q   18922800

typedef __attribute__((ext_vector_type(8))) short short8v;
typedef __attribute__((ext_vector_type(4))) float float4v;

__device__ __forceinline__ ushort f2bf(float f) {
  uint u = __float_as_uint(f);
  uint r = (u + 0x7fffu + ((u >> 16) & 1u)) >> 16;  // RNE
  return (ushort)r;
}
__device__ __forceinline__ uint packbf(float a, float b) {
  __hip_bfloat162 h2 = __float22bfloat162_rn(make_float2(a, b));
  union { __hip_bfloat162 h; uint u; } c;
  c.h = h2;
  return c.u;
}

// Packed upper-triangle index p (0..NT-1) -> (i,j), i<=j.
__device__ __forceinline__ int triOff(int i) {
  return i * 200 - ((i * (i - 1)) >> 1);
}
__device__ __forceinline__ void p2ij(int p, int& io, int& jo) {
  float s = sqrtf((float)(160801 - 8 * p));   // (2N+1)^2 - 8p
  int i = (int)((401.0f - s) * 0.5f);
  if (i < 0) i = 0;
  if (i > 199) i = 199;
  while (i > 0 && triOff(i) > p) --i;
  while (i < 199 && triOff(i + 1) <= p) ++i;
  io = i;
  jo = i + (p - triOff(i));
}

// ---------------------------------------------------------------------------
// A: iteration-invariant part of the GCN update
// ---------------------------------------------------------------------------
__global__ __launch_bounds__(256) void k_base(
    const float* __restrict__ x, const float* __restrict__ dmat,
    const float* __restrict__ label,
    const float* __restrict__ l0w, const float* __restrict__ l0b,
    const float* __restrict__ l1w, const float* __restrict__ l1b,
    const float* __restrict__ l2b, const float* __restrict__ l3b,
    const float* __restrict__ l4w, const float* __restrict__ l4b,
    const float* __restrict__ l5w, const float* __restrict__ l5b,
    float* __restrict__ base) {
  int i = blockIdx.x; int t = threadIdx.x;
  int g = i / MG;
  __shared__ float sv[256];
  __shared__ float sn2[9];
  float v = -1.0f;
  if (t < DEG) {
    int u = (t < i) ? t : t + 1;
    if (u / MG != g) v = dmat[i * DEG + t];
  }
  sv[t] = v;
  __syncthreads();
  for (int k2 = 2; k2 <= 256; k2 <<= 1) {
    for (int jj = k2 >> 1; jj > 0; jj >>= 1) {
      int ixj = t ^ jj;
      if (ixj > t) {
        float a = sv[t], b = sv[ixj];
        bool sw = ((t & k2) == 0) ? (a < b) : (a > b);
        if (sw) { sv[t] = b; sv[ixj] = a; }
      }
      __syncthreads();
    }
  }
  if (t == 0) {
    float tmp[9];
    for (int q = 0; q < 9; q++) tmp[q] = dmat[i * DEG + MG * g + q];
    for (int a2 = 1; a2 < 9; a2++) {
      float key = tmp[a2]; int b2 = a2 - 1;
      while (b2 >= 0 && tmp[b2] < key) { tmp[b2 + 1] = tmp[b2]; b2--; }
      tmp[b2 + 1] = key;
    }
    for (int q = 0; q < 9; q++) sn2[q] = tmp[q];
  }
  __syncthreads();
  if (t < HID) {
    float acc = l0b[t] + l1b[t] + l2b[t] + l3b[t] + l4b[t] + l5b[t];
    acc += x[i * 2 + 0] * l0w[t] + x[i * 2 + 1] * l0w[HID + t];
    for (int k = 0; k < KG; k++) acc += label[i * KG + k] * l1w[k * HID + t];
    for (int q = 0; q < AJR; q++) acc += sv[q] * l4w[q * HID + t];
    for (int q = 0; q < 9; q++) acc += sn2[q] * l5w[q * HID + t];
    base[i * HID + t] = acc;
  }
}

// ---------------------------------------------------------------------------
// B (v10): one GCN step, serial length halved. 256 threads:
//   t<96: n1 partial over j in [0,100);  96<=t<192: n1 partial over [100,199);
//   192<=t<224: n2 (3 dd each, 9-iter loops). Then the dd-matmul is split
//   dd 0..47 / 48..95 across two 96-thread groups and summed via LDS.
// ---------------------------------------------------------------------------
__global__ __launch_bounds__(256) void k_gcn2(
    const float* __restrict__ hin, const float* __restrict__ base,
    const float* __restrict__ w, const float* __restrict__ l2w,
    const float* __restrict__ l3w, float* __restrict__ hout) {
  int i = blockIdx.x; int t = threadIdx.x;
  int g = i / MG;
  __shared__ float pA[HID], wA[HID], pB[HID], wB[HID];
  __shared__ float n1s[HID], n2s[HID];
  __shared__ float m0[HID], m1[HID];
  if (t < HID) {
    float acc = 0.f, ws = 0.f;
    for (int j = 0; j < 100; j++) {
      int u = (j < i) ? j : j + 1;
      if (u / MG != g) {
        float wj = w[i * DEG + j];
        acc += wj * hin[u * HID + t];
        ws += wj;
      }
    }
    pA[t] = acc; wA[t] = ws;
  } else if (t < 2 * HID) {
    int dd = t - HID;
    float acc = 0.f, ws = 0.f;
    for (int j = 100; j < DEG; j++) {
      int u = (j < i) ? j : j + 1;
      if (u / MG != g) {
        float wj = w[i * DEG + j];
        acc += wj * hin[u * HID + dd];
        ws += wj;
      }
    }
    pB[dd] = acc; wB[dd] = ws;
  } else if (t < 224) {
#pragma unroll
    for (int q = 0; q < 3; q++) {
      int dd = (t - 192) * 3 + q;
      float acc = 0.f, ws = 0.f;
      for (int u = MG * g; u < MG * g + MG; u++) {
        if (u == i) continue;
        int j = (u < i) ? u : u - 1;
        float wj = w[i * DEG + j];
        acc += wj * hin[u * HID + dd];
        ws += wj;
      }
      n2s[dd] = acc / ws;
    }
  }
  __syncthreads();
  if (t < HID) n1s[t] = (pA[t] + pB[t]) / (wA[t] + wB[t]);
  __syncthreads();
  if (t < HID) {
    float acc = 0.f;
    for (int dd = 0; dd < 48; dd++)
      acc += n1s[dd] * l2w[dd * HID + t] + n2s[dd] * l3w[dd * HID + t];
    m0[t] = acc;
  } else if (t < 2 * HID) {
    int c = t - HID;
    float acc = 0.f;
    for (int dd = 48; dd < HID; dd++)
      acc += n1s[dd] * l2w[dd * HID + c] + n2s[dd] * l3w[dd * HID + c];
    m1[c] = acc;
  }
  __syncthreads();
  if (t < HID)
    hout[i * HID + t] = fmaxf(base[i * HID + t] + m0[t] + m1[t], 0.f);
}

// ---------------------------------------------------------------------------
// C1: h_full assembly (+ h, h_full outputs)
// ---------------------------------------------------------------------------
__global__ __launch_bounds__(128) void k_hfull(
    const float* __restrict__ h, const float* __restrict__ x,
    const float* __restrict__ label, const int* __restrict__ remain_step,
    float* __restrict__ hfull, float* __restrict__ out_h,
    float* __restrict__ out_hf) {
  int i = blockIdx.x; int t = threadIdx.x;
  if (t < HD) {
    float v;
    if (t < HID) {
      int p = *remain_step;
      int t2 = t & ~1;
      float div = expf(-(float)t2 * (logf(10000.f) / (float)HID));
      float ang = (float)p * div;
      float pe = (t & 1) ? cosf(ang) : sinf(ang);
      float hv = h[i * HID + t];
      out_h[i * HID + t] = hv;
      v = hv + pe;
    } else if (t < HID + 2) {
      v = x[i * 2 + (t - HID)];
    } else {
      v = label[i * KG + (t - HID - 2)];
    }
    hfull[i * HD + t] = v;
    out_hf[i * HD + t] = v;
  }
}

// C2: group means of h_full
__global__ __launch_bounds__(128) void k_gmean(
    const float* __restrict__ hfull, float* __restrict__ gmean) {
  int g = blockIdx.x; int t = threadIdx.x;
  if (t < HD) {
    float s = 0.f;
    for (int q = 0; q < MG; q++) s += hfull[(g * MG + q) * HD + t];
    gmean[g * HD + t] = s * 0.1f;
  }
}

// ---------------------------------------------------------------------------
// D (v10): fused k_wsum + k_kv + k_B; grid (NV, 2) -- column halves double
// the resident-block count (was 200 blocks on 256 CUs).
// ---------------------------------------------------------------------------
__global__ __launch_bounds__(256) void k_kvB(
    const float* __restrict__ hfull, const float* __restrict__ gmean,
    const float* __restrict__ w0, const float* __restrict__ b0v,
    const float* __restrict__ w1, const float* __restrict__ b1v,
    float* __restrict__ khfT, float* __restrict__ vhf,
    float* __restrict__ B1, float* __restrict__ B2) {
  int i = blockIdx.x; int t = threadIdx.x; int g = i / MG;
  int half = blockIdx.y;
  __shared__ float hr[HD], gr[HD];
  if (t < HD) { hr[t] = hfull[i * HD + t]; gr[t] = gmean[g * HD + t]; }
  __syncthreads();
  for (int c = half * 236 + t; c < 236 + half * 236; c += 256) {
    const float* w0c = w0 + c;
    const float* w1c = w1 + c;
    float d0 = 0.f, d1 = 0.f, d2 = 0.f, d3 = 0.f;
    float g2 = 0.f, g3 = 0.f;
    float e0 = 0.f, e1 = 0.f, e2 = 0.f, e3 = 0.f;
    for (int dd = 0; dd < HD; dd++) {
      float hv = hr[dd], gv = gr[dd];
      float a0 = w0c[dd * DM];
      float a1 = w0c[(HD + dd) * DM];
      float a2 = w0c[(2 * HD + dd) * DM];
      float a3 = w0c[(3 * HD + dd) * DM];
      d0 += hv * a0; d1 += hv * a1; d2 += hv * a2; d3 += hv * a3;
      g2 += gv * a2; g3 += gv * a3;
      e0 += hv * w1c[dd * DM];
      e1 += hv * w1c[(HD + dd) * DM];
      e2 += hv * w1c[(2 * HD + dd) * DM];
      e3 += hv * w1c[(3 * HD + dd) * DM];
    }
    float b0c = b0v[c];
    khfT[c * NV + i] = b0c + d0 + d1 + d2 + d3;
    vhf[i * DM + c] = b1v[c] + e0 + e1 + e2 + e3;
    B1[i * DM + c] = d0 + g2;
    B2[i * DM + c] = b0c + d1 + g3;
  }
}

// D4 (v10): score components; grid (NV, 2) -- p-range halves.
__global__ __launch_bounds__(256) void k_SC(
    const float* __restrict__ B1, const float* __restrict__ B2,
    const float* __restrict__ khfT, float* __restrict__ SC1,
    float* __restrict__ SC2) {
  int i = blockIdx.x; int t = threadIdx.x;
  int half = blockIdx.y;
  const float scl = 1.4426950408889634f / sqrtf((float)HD);
  __shared__ float b1r[DM], b2r[DM];
  for (int c = t; c < DM; c += 256) { b1r[c] = B1[i * DM + c]; b2r[c] = B2[i * DM + c]; }
  __syncthreads();
  for (int p = half * 400 + t; p < half * 400 + 400; p += 256) {
    int h = p / NV, k = p - h * NV;
    float s1a = 0.f, s2a = 0.f;
    const float* kc = khfT + (size_t)h * HD * NV + k;
    const float* b1h = b1r + h * HD;
    const float* b2h = b2r + h * HD;
    for (int dd = 0; dd < HD; dd++) {
      float kv = kc[dd * NV];
      s1a += b1h[dd] * kv;
      s2a += b2h[dd] * kv;
    }
    SC1[h * NN + i * NV + k] = s1a * scl;
    SC2[h * NN + i * NV + k] = s2a * scl;
  }
}

// D5: softmax row constants C[h][i][j] = m + log2(l), coalesced row scans.
__global__ __launch_bounds__(256) void k_ml(
    const float* __restrict__ SC1, const float* __restrict__ SC2,
    float* __restrict__ C) {
  int i = blockIdx.x, h = blockIdx.y;
  int t = threadIdx.x;
  __shared__ float s1s[224];
  for (int k = t; k < 224; k += 256)
    s1s[k] = (k < NV) ? SC1[h * NN + i * NV + k] : -1e30f;
  __syncthreads();
  int l = t & 31;
  int g = t >> 5;
  const float* s2b = SC2 + h * NN;
  for (int it = 0; it < 25; ++it) {
    int j = it * 8 + g;
    const float* row = s2b + j * NV;
    float v[7];
#pragma unroll
    for (int e = 0; e < 7; ++e) {
      int k = l + 32 * e;
      v[e] = (k < NV) ? (s1s[k] + row[k]) : -1e30f;
    }
    float m = v[0];
#pragma unroll
    for (int e = 1; e < 7; ++e) m = fmaxf(m, v[e]);
#pragma unroll
    for (int off = 16; off > 0; off >>= 1) m = fmaxf(m, __shfl_xor(m, off, 32));
    float s = 0.f;
#pragma unroll
    for (int e = 0; e < 7; ++e) s += exp2f(v[e] - m);
#pragma unroll
    for (int off = 16; off > 0; off >>= 1) s += __shfl_xor(s, off, 32);
    if (l == 0) C[h * NN + i * NV + j] = m + log2f(s);
  }
}

// ---------------------------------------------------------------------------
// E (v10): merged k_Z + k_ZT. Computes Z[h][k][c] and writes bf16 directly
// into the transposed, zero-padded ZT[c][h*224+k] (512x896). Grid (224, NH):
// k >= NV blocks write zeros (padding rows). Skips the 1.7 MB Z round-trip.
// ---------------------------------------------------------------------------
__global__ __launch_bounds__(256) void k_ZZT(
    const float* __restrict__ vhf, const float* __restrict__ w3,
    ushort* __restrict__ ZT) {
  int k = blockIdx.x, h = blockIdx.y;
  int t = threadIdx.x;
  __shared__ float vr[HD];
  if (k < NV && t < HD) vr[t] = vhf[k * DM + h * HD + t];
  __syncthreads();
  for (int c = t; c < 512; c += 256) {
    float a = 0.f;
    if (k < NV && c < DM) {
      for (int d = 0; d < HD; ++d) a += vr[d] * w3[(h * HD + d) * DM + c];
    }
    ZT[(size_t)c * 896 + h * 224 + k] = f2bf(a);
  }
}

// ---------------------------------------------------------------------------
// F (= round-4 proven kernel, 110 us): fused attention+output GEMM over
// UNIQUE row pairs. 64 packed rows x 128 cols, grid (4, 315). Mirror write.
// ---------------------------------------------------------------------------
__global__ __launch_bounds__(256) void k_sfusedT2(
    const float* __restrict__ SC1, const float* __restrict__ SC2,
    const float* __restrict__ C, const ushort* __restrict__ ZT,
    const float* __restrict__ b3, float* __restrict__ outS) {
  int t = threadIdx.x;
  int c0 = blockIdx.x * 128, p0 = blockIdx.y * 64;
  int lane = t & 63, wm = t >> 6;
  int frow = lane & 15, quad = lane >> 4;
  __shared__ __align__(16) ushort Bs[128 * 40];
  int p = p0 + wm * 16 + frow;
  bool bval = (p < NT);
  int iA = 0, jA = 0;
  if (bval) p2ij(p, iA, jA);
  int iN = iA * NV, jN = jA * NV;
  float4v acc[8];
#pragma unroll
  for (int n = 0; n < 8; ++n) acc[n] = (float4v)(0.f);
  int rB = t >> 1, khB = (t & 1) * 16;

  for (int h = 0; h < NH; ++h) {
    int hb = h * NN;
    const float* s1h = SC1 + hb;
    const float* s2h = SC2 + hb;
    float ci = bval ? C[hb + iN + jA] : 0.f;
    float cj = bval ? C[hb + jN + iA] : 0.f;
    for (int ks = 0; ks < 7; ++ks) {
      int kb = ks * 32 + quad * 8;
      bool kvalid = (kb + 7 < NV);
      union { uint4 q; short8v v; } af;
      if (bval && kvalid) {
        const float* q1i = s1h + iN + kb;
        const float* q2i = s2h + iN + kb;
        const float* q1j = s1h + jN + kb;
        const float* q2j = s2h + jN + kb;
        float4 a0 = *(const float4*)q1i,   a0b = *(const float4*)(q1i + 4);
        float4 b0 = *(const float4*)q2j,   b0b = *(const float4*)(q2j + 4);
        float4 d0 = *(const float4*)q1j,   d0b = *(const float4*)(q1j + 4);
        float4 e0 = *(const float4*)q2i,   e0b = *(const float4*)(q2i + 4);
        float p0_ = exp2f(a0.x + b0.x - ci) + exp2f(d0.x + e0.x - cj);
        float p1_ = exp2f(a0.y + b0.y - ci) + exp2f(d0.y + e0.y - cj);
        float p2_ = exp2f(a0.z + b0.z - ci) + exp2f(d0.z + e0.z - cj);
        float p3_ = exp2f(a0.w + b0.w - ci) + exp2f(d0.w + e0.w - cj);
        float p4_ = exp2f(a0b.x + b0b.x - ci) + exp2f(d0b.x + e0b.x - cj);
        float p5_ = exp2f(a0b.y + b0b.y - ci) + exp2f(d0b.y + e0b.y - cj);
        float p6_ = exp2f(a0b.z + b0b.z - ci) + exp2f(d0b.z + e0b.z - cj);
        float p7_ = exp2f(a0b.w + b0b.w - ci) + exp2f(d0b.w + e0b.w - cj);
        af.q.x = packbf(p0_, p1_);
        af.q.y = packbf(p2_, p3_);
        af.q.z = packbf(p4_, p5_);
        af.q.w = packbf(p6_, p7_);
      } else {
        af.q = make_uint4(0, 0, 0, 0);
      }
      const uint4* wp = (const uint4*)(ZT + (size_t)(c0 + rB) * 896 +
                                       h * 224 + ks * 32 + khB);
      uint4 bq0 = wp[0], bq1 = wp[1];
      __syncthreads();
      *(uint4*)&Bs[rB * 40 + khB] = bq0;
      *(uint4*)&Bs[rB * 40 + khB + 8] = bq1;
      __syncthreads();
#pragma unroll
      for (int n = 0; n < 8; ++n) {
        short8v bf = *(const short8v*)&Bs[(n * 16 + frow) * 40 + quad * 8];
        acc[n] = __builtin_amdgcn_mfma_f32_16x16x32_bf16(af.v, bf, acc[n],
                                                         0, 0, 0);
      }
    }
  }
  int ie[4], je[4];
#pragma unroll
  for (int r2 = 0; r2 < 4; ++r2) {
    int pe = p0 + wm * 16 + quad * 4 + r2;
    if (pe < NT) {
      p2ij(pe, ie[r2], je[r2]);
    } else {
      ie[r2] = -1; je[r2] = 0;
    }
  }
#pragma unroll
  for (int n = 0; n < 8; ++n) {
    int c = c0 + n * 16 + frow;
    if (c >= DM) continue;
    float bb = 2.0f * b3[c];
#pragma unroll
    for (int r2 = 0; r2 < 4; ++r2) {
      int ii = ie[r2];
      if (ii < 0) continue;
      int jj = je[r2];
      float v = acc[n][r2] + bb;
      outS[(size_t)(ii * NV + jj) * DM + c] = v;
      if (ii != jj) outS[(size_t)(jj * NV + ii) * DM + c] = v;
    }
  }
}

// ---------------------------------------------------------------------------
// G (v10): Q_sa = relu(S@v1+b1)@v2 + b2 over unique rows; 32 rows/block
// (grid 629 vs old 315: 2x resident blocks), 59-col chunks (16 barriers vs
// 118), conflict-free padded LDS. Mirror write.
// ---------------------------------------------------------------------------
__global__ __launch_bounds__(256) void k_qsaT2(
    const float* __restrict__ S, const float* __restrict__ v1w,
    const float* __restrict__ v1b, const float* __restrict__ v2w,
    const float* __restrict__ v2b, float* __restrict__ outQ) {
  __shared__ float Ss[32][61];
  __shared__ float V1s[59][48];
  __shared__ float Ts[32][49];
  __shared__ int rowI[32], rowJ[32], rowOfs[32];
  int t = threadIdx.x;
  int p0b = blockIdx.x * 32;
  if (t < 32) {
    int p = p0b + t;
    if (p < NT) {
      int ii, jj; p2ij(p, ii, jj);
      rowI[t] = ii; rowJ[t] = jj; rowOfs[t] = ii * NV + jj;
    } else {
      rowI[t] = -1; rowJ[t] = 0; rowOfs[t] = 0;
    }
  }
  int ty2 = (t >> 4) * 2;     // rows ty2, ty2+1
  int tx3 = (t & 15) * 3;     // q outputs tx3..tx3+2
  float a00 = 0.f, a01 = 0.f, a02 = 0.f, a10 = 0.f, a11 = 0.f, a12 = 0.f;
  for (int k0 = 0; k0 < DM; k0 += 59) {
    __syncthreads();  // rowOfs ready (1st iter); previous compute done (rest)
    for (int e = t; e < 32 * 59; e += 256) {
      int r = e / 59, cc = e - r * 59;
      Ss[r][cc] = S[(size_t)rowOfs[r] * DM + k0 + cc];
    }
    for (int e = t; e < 59 * 48; e += 256) {
      int kk = e / 48, cc = e - kk * 48;
      V1s[kk][cc] = v1w[(size_t)(k0 + kk) * 48 + cc];
    }
    __syncthreads();
    for (int kk = 0; kk < 59; ++kk) {
      float s0 = Ss[ty2][kk], s1 = Ss[ty2 + 1][kk];
      float w0_ = V1s[kk][tx3], w1_ = V1s[kk][tx3 + 1], w2_ = V1s[kk][tx3 + 2];
      a00 += s0 * w0_; a01 += s0 * w1_; a02 += s0 * w2_;
      a10 += s1 * w0_; a11 += s1 * w1_; a12 += s1 * w2_;
    }
  }
  float b0 = v1b[tx3], b1 = v1b[tx3 + 1], b2 = v1b[tx3 + 2];
  Ts[ty2][tx3] = fmaxf(a00 + b0, 0.f);
  Ts[ty2][tx3 + 1] = fmaxf(a01 + b1, 0.f);
  Ts[ty2][tx3 + 2] = fmaxf(a02 + b2, 0.f);
  Ts[ty2 + 1][tx3] = fmaxf(a10 + b0, 0.f);
  Ts[ty2 + 1][tx3 + 1] = fmaxf(a11 + b1, 0.f);
  Ts[ty2 + 1][tx3 + 2] = fmaxf(a12 + b2, 0.f);
  __syncthreads();
  if (t < 32 && rowI[t] >= 0) {
    float q = v2b[0];
    for (int c = 0; c < 48; c++) q += Ts[t][c] * v2w[c];
    int ii = rowI[t], jj = rowJ[t];
    outQ[ii * NV + jj] = q;
    if (ii != jj) outQ[jj * NV + ii] = q;
  }
}

// ---------------------------------------------------------------------------
extern "C" void kernel_launch(void* const* d_in, const int* in_sizes, int n_in,
                              void* d_out, int out_size, void* d_ws,
                              size_t ws_size, hipStream_t stream) {
  const float* x = (const float*)d_in[0];
  const float* label = (const float*)d_in[1];
  const float* h0 = (const float*)d_in[2];
  const float* w = (const float*)d_in[3];
  const float* dmat = (const float*)d_in[4];
  const float* l0w = (const float*)d_in[5];
  const float* l0b = (const float*)d_in[6];
  const float* l1w = (const float*)d_in[7];
  const float* l1b = (const float*)d_in[8];
  const float* l2w = (const float*)d_in[9];
  const float* l2b = (const float*)d_in[10];
  const float* l3w = (const float*)d_in[11];
  const float* l3b = (const float*)d_in[12];
  const float* l4w = (const float*)d_in[13];
  const float* l4b = (const float*)d_in[14];
  const float* l5w = (const float*)d_in[15];
  const float* l5b = (const float*)d_in[16];
  const float* w0 = (const float*)d_in[17];
  const float* b0v = (const float*)d_in[18];
  const float* w1 = (const float*)d_in[19];
  const float* b1v = (const float*)d_in[20];
  const float* w3 = (const float*)d_in[21];
  const float* b3 = (const float*)d_in[22];
  const float* v1w = (const float*)d_in[23];
  const float* v1b = (const float*)d_in[24];
  const float* v2w = (const float*)d_in[25];
  const float* v2b = (const float*)d_in[26];
  const int* remain_step = (const int*)d_in[29];

  float* ws = (float*)d_ws;
  float* base = ws + WS_BASE;
  float* h1 = ws + WS_H1;
  float* h2 = ws + WS_H2;
  float* hfull = ws + WS_HFULL;
  float* gmean = ws + WS_GMEAN;
  float* khfT = ws + WS_KHF;
  float* vhf = ws + WS_VHF;
  float* B1 = ws + WS_B1;
  float* B2 = ws + WS_B2;
  float* SC1 = ws + WS_SC1;
  float* SC2 = ws + WS_SC2;
  ushort* ZT = (ushort*)(ws + WS_ZT);
  float* C = ws + WS_B1;  // reuses B1/B2 slots after k_SC

  float* outS = (float*)d_out;
  float* outH = outS + OFF_H;
  float* outHF = outS + OFF_HF;
  float* outQ = outS + OFF_Q;

  k_base<<<NV, 256, 0, stream>>>(x, dmat, label, l0w, l0b, l1w, l1b, l2b, l3b,
                                 l4w, l4b, l5w, l5b, base);
  k_gcn2<<<NV, 256, 0, stream>>>(h0, base, w, l2w, l3w, h1);
  k_gcn2<<<NV, 256, 0, stream>>>(h1, base, w, l2w, l3w, h2);
  k_hfull<<<NV, 128, 0, stream>>>(h2, x, label, remain_step, hfull, outH, outHF);
  k_gmean<<<KG, 128, 0, stream>>>(hfull, gmean);
  k_kvB<<<dim3(NV, 2), 256, 0, stream>>>(hfull, gmean, w0, b0v, w1, b1v, khfT,
                                         vhf, B1, B2);
  k_ZZT<<<dim3(224, NH), 256, 0, stream>>>(vhf, w3, ZT);
  k_SC<<<dim3(NV, 2), 256, 0, stream>>>(B1, B2, khfT, SC1, SC2);
  k_ml<<<dim3(NV, NH), 256, 0, stream>>>(SC1, SC2, C);
  k_sfusedT2<<<dim3(4, NTP / 64), 256, 0, stream>>>(SC1, SC2, C, ZT, b3, outS);
  k_qsaT2<<<(NT + 31) / 32, 256, 0, stream>>>(outS, v1w, v1b, v2w, v2b, outQ);
}